// Round 7
// baseline (929.766 us; speedup 1.0000x reference)
//
#include <hip/hip_runtime.h>
#include <hip/hip_bf16.h>

#define NEG_SLOPE 0.2f
#define BN_EPS 1e-5f
#define BSHIFT 7   // 128 nodes per bucket; src packed in low 25 bits (N < 2^25)

typedef unsigned int uint32;
typedef unsigned short ushort16;
typedef __attribute__((ext_vector_type(8))) short bf16x8;
typedef __attribute__((ext_vector_type(4))) float f32x4;

__device__ __forceinline__ ushort16 f2bf(float f) {
    uint32 u = __float_as_uint(f);
    u = (u + 0x7fff + ((u >> 16) & 1)) >> 16;  // round-to-nearest-even
    return (ushort16)u;
}
__device__ __forceinline__ float bfu_lo(uint32 u) { return __uint_as_float(u << 16); }
__device__ __forceinline__ float bfu_hi(uint32 u) { return __uint_as_float(u & 0xffff0000u); }

// ============================ CSR construction ============================
__global__ void deg_count(const int* __restrict__ ei, int E, int Etot, int* __restrict__ deg) {
    int i = blockIdx.x * blockDim.x + threadIdx.x;
    if (i >= Etot) return;
    int d = (i < E) ? ei[E + i] : i - E;
    atomicAdd(&deg[d], 1);
}

__global__ void scan_block(const int* __restrict__ deg, int* __restrict__ base,
                           int* __restrict__ bsum, int n) {
    __shared__ int s[1024];
    int gid = blockIdx.x * 1024 + threadIdx.x;
    int v = (gid < n) ? deg[gid] : 0;
    s[threadIdx.x] = v;
    __syncthreads();
    for (int off = 1; off < 1024; off <<= 1) {
        int t = (threadIdx.x >= off) ? s[threadIdx.x - off] : 0;
        __syncthreads();
        s[threadIdx.x] += t;
        __syncthreads();
    }
    if (gid < n) base[gid] = s[threadIdx.x] - v;  // exclusive
    if (threadIdx.x == 1023) bsum[blockIdx.x] = s[1023];
}

// single-wave parallel exclusive scan of block sums (nb <= 64)
__global__ void scan_bsum(int* __restrict__ bsum, int nb) {
    int t = threadIdx.x;
    int orig = (t < nb) ? bsum[t] : 0;
    int v = orig;
#pragma unroll
    for (int off = 1; off < 64; off <<= 1) {
        int u = __shfl_up(v, off, 64);
        if (t >= off) v += u;
    }
    if (t < nb) bsum[t] = v - orig;
}

__global__ void scan_add(int* __restrict__ base, const int* __restrict__ bsum, int n) {
    int gid = blockIdx.x * 1024 + threadIdx.x;
    if (gid < n) base[gid] += bsum[blockIdx.x];
}

// ---- bucketed scatter: phase A = histogram + scan + coalescing bucket scatter ----
__global__ void bucket_hist(const int* __restrict__ ei, int E, int Etot,
                            int* __restrict__ bcnt) {
    int i = blockIdx.x * blockDim.x + threadIdx.x;
    if (i >= Etot) return;
    int d = (i < E) ? ei[E + i] : i - E;
    atomicAdd(&bcnt[d >> BSHIFT], 1);
}

// single block (1024 threads): exclusive scan bcnt -> bbase (nb+1), copy to bcur
__global__ void bucket_scan(const int* __restrict__ bcnt, int* __restrict__ bbase,
                            int* __restrict__ bcur, int nb, int Etot) {
    __shared__ int s[1024];
    int t = threadIdx.x;
    int v = (t < nb) ? bcnt[t] : 0;
    s[t] = v;
    __syncthreads();
    for (int off = 1; off < 1024; off <<= 1) {
        int u = (t >= off) ? s[t - off] : 0;
        __syncthreads();
        s[t] += u;
        __syncthreads();
    }
    if (t < nb) { int e = s[t] - v; bbase[t] = e; bcur[t] = e; }
    if (t == 0) bbase[nb] = Etot;
}

// pack (dst_local<<25 | src); atomicAdd on bucket cursor hands out sequential
// positions -> concurrent same-bucket writes coalesce into full L2 lines.
__global__ void bucket_scatter(const int* __restrict__ ei, int E, int Etot,
                               int* __restrict__ bcur, uint32* __restrict__ ebuf) {
    int i = blockIdx.x * blockDim.x + threadIdx.x;
    if (i >= Etot) return;
    int s_, d_;
    if (i < E) { s_ = ei[i]; d_ = ei[E + i]; }
    else       { s_ = d_ = i - E; }
    int pos = atomicAdd(&bcur[d_ >> BSHIFT], 1);
    ebuf[pos] = ((uint32)(d_ & ((1 << BSHIFT) - 1)) << 25) | (uint32)s_;
}

// phase B: block per bucket, LDS cursors (no global atomics); csr writes
// confined to the bucket's ~9KB window.
__global__ __launch_bounds__(256) void bucket_place(
    const int* __restrict__ bbase, const uint32* __restrict__ ebuf,
    const int* __restrict__ base, int* __restrict__ csr_src) {
    const int bk = blockIdx.x;
    __shared__ int lcur[1 << BSHIFT];
    const int t = threadIdx.x;
    if (t < (1 << BSHIFT)) lcur[t] = 0;
    __syncthreads();
    const int beg = bbase[bk], end = bbase[bk + 1];
    const int node0 = bk << BSHIFT;
    for (int i = beg + t; i < end; i += 256) {
        uint32 pk = ebuf[i];
        int s_ = (int)(pk & 0x1FFFFFFu);
        int dl = (int)(pk >> 25);
        int pos = base[node0 + dl] + atomicAdd(&lcur[dl], 1);
        csr_src[pos] = s_;
    }
}

// gstart[g] = first node with batch[node] >= g (batch sorted); gstart[G] = N.
__global__ void graph_bounds(const int* __restrict__ batch, int N, int G,
                             int* __restrict__ gstart) {
    int g = blockIdx.x * blockDim.x + threadIdx.x;
    if (g > G) return;
    if (g == G) { gstart[G] = N; return; }
    int lo = 0, hi = N;
    while (lo < hi) { int mid = (lo + hi) >> 1; if (batch[mid] < g) lo = mid + 1; else hi = mid; }
    gstart[g] = lo;
}

// ================== pack W (+ attention columns) transposed, bf16 ==================
template <int OC, int C>
__global__ void pack_w(const float* __restrict__ W, const float* __restrict__ a_s,
                       const float* __restrict__ a_d, ushort16* __restrict__ wt) {
    const int col = blockIdx.x;
    const int k = threadIdx.x;  // 0..127
    float v = 0.f;
    if (col < OC) {
        v = W[k * OC + col];
    } else if (col < OC + 2) {
        int hh = col - OC;
        float s = 0.f;
        for (int c = 0; c < C; ++c) s += W[k * OC + hh * C + c] * a_s[hh * C + c];
        v = s;
    } else if (col < OC + 4) {
        int hh = col - OC - 2;
        float s = 0.f;
        for (int c = 0; c < C; ++c) s += W[k * OC + hh * C + c] * a_d[hh * C + c];
        v = s;
    }
    wt[(size_t)col * 128 + k] = f2bf(v);
}

// ==================== MFMA GEMM: h = x @ Wext (K=128) ====================
template <int OC, int NT, bool AF32>
__global__ __launch_bounds__(256) void gemm_mfma(
    const void* __restrict__ xin, const ushort16* __restrict__ wt,
    ushort16* __restrict__ h, float4* __restrict__ att, int N) {
    const int wave = threadIdx.x >> 6, lane = threadIdx.x & 63;
    const int tile = blockIdx.x * 4 + wave;
    if (tile * 16 >= N) return;
    const int m = lane & 15, quad = lane >> 4;
    const int node = tile * 16 + m;

    bf16x8 a[4];
    if (AF32) {
        const float* xr = (const float*)xin + (size_t)node * 128 + quad * 8;
#pragma unroll
        for (int c = 0; c < 4; ++c) {
            float4 u = *(const float4*)(xr + c * 32);
            float4 v = *(const float4*)(xr + c * 32 + 4);
            bf16x8 t;
            t[0] = (short)f2bf(u.x); t[1] = (short)f2bf(u.y);
            t[2] = (short)f2bf(u.z); t[3] = (short)f2bf(u.w);
            t[4] = (short)f2bf(v.x); t[5] = (short)f2bf(v.y);
            t[6] = (short)f2bf(v.z); t[7] = (short)f2bf(v.w);
            a[c] = t;
        }
    } else {
        const ushort16* xr = (const ushort16*)xin + (size_t)node * 128 + quad * 8;
#pragma unroll
        for (int c = 0; c < 4; ++c) a[c] = *(const bf16x8*)(xr + c * 32);
    }

    for (int t = 0; t < NT; ++t) {
        const ushort16* wr = wt + ((size_t)(t * 16 + m)) * 128 + quad * 8;
        bf16x8 b[4];
#pragma unroll
        for (int c = 0; c < 4; ++c) b[c] = *(const bf16x8*)(wr + c * 32);
        f32x4 acc = {0.f, 0.f, 0.f, 0.f};
#pragma unroll
        for (int c = 0; c < 4; ++c)
            acc = __builtin_amdgcn_mfma_f32_16x16x32_bf16(a[c], b[c], acc, 0, 0, 0);
        if (t * 16 < OC) {
#pragma unroll
            for (int r = 0; r < 4; ++r) {
                int nrow = tile * 16 + quad * 4 + r;
                h[(size_t)nrow * OC + t * 16 + m] = f2bf(acc[r]);
            }
        } else if (m < 4) {
#pragma unroll
            for (int r = 0; r < 4; ++r) {
                int nrow = tile * 16 + quad * 4 + r;
                ((float*)(att + nrow))[m] = acc[r];
            }
        }
    }
}

// ================= layer-1 gather: softmax-agg + bias + BN + ReLU -> bf16 =================
__global__ __launch_bounds__(256) void gat_gather1(
    const int* __restrict__ base, const int* __restrict__ csr_src, int Etot, int N,
    const ushort16* __restrict__ h, const float4* __restrict__ att,
    const float* __restrict__ b, const float* __restrict__ g, const float* __restrict__ be,
    const float* __restrict__ mu, const float* __restrict__ var,
    ushort16* __restrict__ outb) {
    const int node = __builtin_amdgcn_readfirstlane(blockIdx.x * 4 + (threadIdx.x >> 6));
    if (node >= N) return;
    const int t = threadIdx.x & 63;
    const int half = t >> 5;
    const int q = t & 31;      // channels 4q..4q+3
    const int hh = q >> 4;     // head
    const int beg = base[node];
    const int end = (node + 1 < N) ? base[node + 1] : Etot;
    const int deg = end - beg;
    const int nk = (deg - half + 1) >> 1;
    const int nkmax = (deg + 1) >> 1;
    const float4 adn = att[node];
    const float advh = hh ? adn.w : adn.z;

    float a0 = 0.f, a1 = 0.f, a2 = 0.f, a3 = 0.f, ssum = 0.f;
    constexpr int U = 4;
    for (int k = 0; k < nkmax; k += U) {
        int sidx[U];
        float msk[U];
#pragma unroll
        for (int j = 0; j < U; ++j) {
            int kk = k + j;
            bool ok = kk < nk;
            sidx[j] = csr_src[beg + (ok ? 2 * kk + half : 0)];
            msk[j] = ok ? 1.f : 0.f;
        }
        float4 av[U];
        uint2 hv[U];
#pragma unroll
        for (int j = 0; j < U; ++j) {
            av[j] = att[sidx[j]];
            hv[j] = *(const uint2*)(h + (size_t)sidx[j] * 128 + 4 * q);
        }
#pragma unroll
        for (int j = 0; j < U; ++j) {
            float ev = (hh ? av[j].y : av[j].x) + advh;
            ev = ev > 0.f ? ev : NEG_SLOPE * ev;
            float ex = __expf(ev) * msk[j];
            a0 += ex * bfu_lo(hv[j].x);
            a1 += ex * bfu_hi(hv[j].x);
            a2 += ex * bfu_lo(hv[j].y);
            a3 += ex * bfu_hi(hv[j].y);
            ssum += ex;
        }
    }
    a0 += __shfl_xor(a0, 32, 64);
    a1 += __shfl_xor(a1, 32, 64);
    a2 += __shfl_xor(a2, 32, 64);
    a3 += __shfl_xor(a3, 32, 64);
    ssum += __shfl_xor(ssum, 32, 64);
    if (half == 0) {
        const float inv = 1.f / (ssum + 1e-16f);
        const int c0 = 4 * q;
        float4 bb = *(const float4*)(b + c0);
        float4 gg = *(const float4*)(g + c0);
        float4 ee = *(const float4*)(be + c0);
        float4 mm = *(const float4*)(mu + c0);
        float4 vv = *(const float4*)(var + c0);
        float v0 = a0 * inv + bb.x, v1 = a1 * inv + bb.y;
        float v2 = a2 * inv + bb.z, v3 = a3 * inv + bb.w;
        v0 = fmaxf((v0 - mm.x) * rsqrtf(vv.x + BN_EPS) * gg.x + ee.x, 0.f);
        v1 = fmaxf((v1 - mm.y) * rsqrtf(vv.y + BN_EPS) * gg.y + ee.y, 0.f);
        v2 = fmaxf((v2 - mm.z) * rsqrtf(vv.z + BN_EPS) * gg.z + ee.z, 0.f);
        v3 = fmaxf((v3 - mm.w) * rsqrtf(vv.w + BN_EPS) * gg.w + ee.w, 0.f);
        uint2 r;
        r.x = (uint32)f2bf(v0) | ((uint32)f2bf(v1) << 16);
        r.y = (uint32)f2bf(v2) | ((uint32)f2bf(v3) << 16);
        *(uint2*)(outb + (size_t)node * 128 + c0) = r;
    }
}

// ====== layer-2 gather: softmax-agg + head-mean + bias + BN -> node_out ======
__global__ __launch_bounds__(256) void gat_gather2(
    const int* __restrict__ base, const int* __restrict__ csr_src, int Etot, int N,
    const ushort16* __restrict__ h2, const float4* __restrict__ att,
    const float* __restrict__ b2, const float* __restrict__ g, const float* __restrict__ be,
    const float* __restrict__ mu, const float* __restrict__ var,
    float* __restrict__ node_out) {
    const int node = __builtin_amdgcn_readfirstlane(blockIdx.x * 4 + (threadIdx.x >> 6));
    if (node >= N) return;
    const int t = threadIdx.x & 63;
    const int half = t >> 5;
    const int q = t & 31;      // channels 2q, 2q+1
    const int hh = q >> 4;     // head
    const int beg = base[node];
    const int end = (node + 1 < N) ? base[node + 1] : Etot;
    const int deg = end - beg;
    const int nk = (deg - half + 1) >> 1;
    const int nkmax = (deg + 1) >> 1;
    const float4 adn = att[node];
    const float advh = hh ? adn.w : adn.z;

    float accx = 0.f, accy = 0.f, ssum = 0.f;
    constexpr int U = 4;
    for (int k = 0; k < nkmax; k += U) {
        int sidx[U];
        float msk[U];
#pragma unroll
        for (int j = 0; j < U; ++j) {
            int kk = k + j;
            bool ok = kk < nk;
            sidx[j] = csr_src[beg + (ok ? 2 * kk + half : 0)];
            msk[j] = ok ? 1.f : 0.f;
        }
        float4 av[U];
        uint32 hv[U];
#pragma unroll
        for (int j = 0; j < U; ++j) {
            av[j] = att[sidx[j]];
            hv[j] = *(const uint32*)(h2 + (size_t)sidx[j] * 64 + 2 * q);
        }
#pragma unroll
        for (int j = 0; j < U; ++j) {
            float ev = (hh ? av[j].y : av[j].x) + advh;
            ev = ev > 0.f ? ev : NEG_SLOPE * ev;
            float ex = __expf(ev) * msk[j];
            accx += ex * bfu_lo(hv[j]);
            accy += ex * bfu_hi(hv[j]);
            ssum += ex;
        }
    }
    accx += __shfl_xor(accx, 32, 64);
    accy += __shfl_xor(accy, 32, 64);
    ssum += __shfl_xor(ssum, 32, 64);
    const float inv = 1.f / (ssum + 1e-16f);
    float v0 = accx * inv;
    float v1 = accy * inv;
    float p0 = __shfl(v0, (t & 15) + 16, 64);
    float p1 = __shfl(v1, (t & 15) + 16, 64);
    if (t < 16) {
        const int c0 = 2 * t;
        float m0 = 0.5f * (v0 + p0) + b2[c0];
        float m1 = 0.5f * (v1 + p1) + b2[c0 + 1];
        m0 = (m0 - mu[c0]) * rsqrtf(var[c0] + BN_EPS) * g[c0] + be[c0];
        m1 = (m1 - mu[c0 + 1]) * rsqrtf(var[c0 + 1] + BN_EPS) * g[c0 + 1] + be[c0 + 1];
        *(float2*)(node_out + (size_t)node * 32 + c0) = make_float2(m0, m1);
    }
}

// ============ block-per-graph: mean over nodes + log_softmax (32 classes) ============
__global__ __launch_bounds__(256) void pool_logsoftmax(
    const float* __restrict__ node_out, const int* __restrict__ gstart,
    float* __restrict__ out) {
    const int gidx = blockIdx.x;
    const int tid = threadIdx.x;
    const int c = tid & 31, r = tid >> 5;
    const int n0 = gstart[gidx], n1 = gstart[gidx + 1];
    float s = 0.f;
    for (int n = n0 + r; n < n1; n += 8) s += node_out[(size_t)n * 32 + c];
    __shared__ float red[8][32];
    red[r][c] = s;
    __syncthreads();
    if (r == 0) {
        float tot = red[0][c];
#pragma unroll
        for (int k = 1; k < 8; ++k) tot += red[k][c];
        float v = tot / fmaxf((float)(n1 - n0), 1.f);
        float m = v;
#pragma unroll
        for (int off = 16; off >= 1; off >>= 1) m = fmaxf(m, __shfl_xor(m, off, 64));
        float ex = __expf(v - m);
        float ssum = ex;
#pragma unroll
        for (int off = 16; off >= 1; off >>= 1) ssum += __shfl_xor(ssum, off, 64);
        out[gidx * 32 + c] = v - m - logf(ssum);
    }
}

extern "C" void kernel_launch(void* const* d_in, const int* in_sizes, int n_in,
                              void* d_out, int out_size, void* d_ws, size_t ws_size,
                              hipStream_t stream) {
    const float* x   = (const float*)d_in[0];
    const int* ei    = (const int*)d_in[1];
    const int* batch = (const int*)d_in[2];
    const float* W1  = (const float*)d_in[3];
    const float* as1 = (const float*)d_in[4];
    const float* ad1 = (const float*)d_in[5];
    const float* b1  = (const float*)d_in[6];
    const float* g1  = (const float*)d_in[7];
    const float* be1 = (const float*)d_in[8];
    const float* mu1 = (const float*)d_in[9];
    const float* vr1 = (const float*)d_in[10];
    const float* W2  = (const float*)d_in[11];
    const float* as2 = (const float*)d_in[12];
    const float* ad2 = (const float*)d_in[13];
    const float* b2  = (const float*)d_in[14];
    const float* g2  = (const float*)d_in[15];
    const float* be2 = (const float*)d_in[16];
    const float* mu2 = (const float*)d_in[17];
    const float* vr2 = (const float*)d_in[18];
    float* out = (float*)d_out;

    const int N = in_sizes[0] / 128;
    const int E = in_sizes[1] / 2;
    const int Etot = E + N;
    const int G = out_size / 32;
    const int NB = (N + 1023) / 1024;
    const int nbuck = (N + (1 << BSHIFT) - 1) >> BSHIFT;
    const int ntile = (N + 15) / 16;
    const int gemm_grid = (ntile + 3) / 4;

    // ---- workspace layout (units: floats; keep every region 16B-aligned) ----
    float* p = (float*)d_ws;
    size_t o = 0;
    auto al = [&]() { o = (o + 3) & ~(size_t)3; };
    ushort16* h1b   = (ushort16*)(p + o); o += (size_t)N * 64;  al();  // N*128 bf16
    ushort16* agg1b = (ushort16*)(p + o); o += (size_t)N * 64;  al();  // N*128 bf16
    ushort16* h2b   = (ushort16*)(p + o); o += (size_t)N * 32;  al();  // N*64 bf16
    float4* att1 = (float4*)(p + o); o += (size_t)N * 4;  al();
    float4* att2 = (float4*)(p + o); o += (size_t)N * 4;  al();
    float* nodeo = p + o; o += (size_t)N * 32; al();
    ushort16* wt1 = (ushort16*)(p + o); o += (size_t)144 * 64; al();   // 144x128 bf16
    ushort16* wt2 = (ushort16*)(p + o); o += (size_t)80 * 64;  al();   // 80x128 bf16
    int* csr_src = (int*)(p + o); o += (size_t)Etot; al();
    uint32* ebuf = (uint32*)(p + o); o += (size_t)Etot; al();
    int* base    = (int*)(p + o); o += (size_t)N;    al();
    int* bsum    = (int*)(p + o); o += 256;
    int* gstart  = (int*)(p + o); o += (size_t)G + 4; al();
    int* bbase   = (int*)(p + o); o += (size_t)nbuck + 4; al();
    int* bcur    = (int*)(p + o); o += (size_t)nbuck + 4; al();
    // zero-initialized region (one memset):
    float* zbase = p + o;
    int* deg     = (int*)(p + o); o += (size_t)N; al();
    int* bcnt    = (int*)(p + o); o += (size_t)nbuck + 4; al();
    const size_t zbytes = (size_t)(p + o - zbase) * sizeof(float);
    hipMemsetAsync(zbase, 0, zbytes, stream);

    // ---- per-node degree + exclusive scan ----
    deg_count<<<(Etot + 255) / 256, 256, 0, stream>>>(ei, E, Etot, deg);
    scan_block<<<NB, 1024, 0, stream>>>(deg, base, bsum, N);
    scan_bsum<<<1, 64, 0, stream>>>(bsum, NB);
    scan_add<<<NB, 1024, 0, stream>>>(base, bsum, N);
    // ---- bucketed CSR scatter ----
    bucket_hist<<<(Etot + 255) / 256, 256, 0, stream>>>(ei, E, Etot, bcnt);
    bucket_scan<<<1, 1024, 0, stream>>>(bcnt, bbase, bcur, nbuck, Etot);
    bucket_scatter<<<(Etot + 255) / 256, 256, 0, stream>>>(ei, E, Etot, bcur, ebuf);
    bucket_place<<<nbuck, 256, 0, stream>>>(bbase, ebuf, base, csr_src);
    // ---- graph bounds + weight pack ----
    graph_bounds<<<(G + 256) / 256, 256, 0, stream>>>(batch, N, G, gstart);
    pack_w<128, 64><<<144, 128, 0, stream>>>(W1, as1, ad1, wt1);
    pack_w<64, 32><<<80, 128, 0, stream>>>(W2, as2, ad2, wt2);

    // ---- layer 1 ----
    gemm_mfma<128, 9, true><<<gemm_grid, 256, 0, stream>>>(x, wt1, h1b, att1, N);
    gat_gather1<<<(N + 3) / 4, 256, 0, stream>>>(base, csr_src, Etot, N, h1b, att1,
                                                 b1, g1, be1, mu1, vr1, agg1b);
    // ---- layer 2 ----
    gemm_mfma<64, 5, false><<<gemm_grid, 256, 0, stream>>>(agg1b, wt2, h2b, att2, N);
    gat_gather2<<<(N + 3) / 4, 256, 0, stream>>>(base, csr_src, Etot, N, h2b, att2,
                                                 b2, g2, be2, mu2, vr2, nodeo);

    // ---- epilogue ----
    pool_logsoftmax<<<G, 256, 0, stream>>>(nodeo, gstart, out);
}

// Round 8
// 423.224 us; speedup vs baseline: 2.1969x; 2.1969x over previous
//
#include <hip/hip_runtime.h>
#include <hip/hip_bf16.h>

#define NEG_SLOPE 0.2f
#define BN_EPS 1e-5f
#define BSHIFT 7          // 128 nodes per bucket; src packed in low 25 bits (N < 2^25)
#define P_PART 256        // scatter partitions
#define MAXB 512          // max buckets supported (N <= 65536)

typedef unsigned int uint32;
typedef unsigned short ushort16;
typedef __attribute__((ext_vector_type(8))) short bf16x8;
typedef __attribute__((ext_vector_type(4))) float f32x4;

__device__ __forceinline__ ushort16 f2bf(float f) {
    uint32 u = __float_as_uint(f);
    u = (u + 0x7fff + ((u >> 16) & 1)) >> 16;  // round-to-nearest-even
    return (ushort16)u;
}
__device__ __forceinline__ float bfu_lo(uint32 u) { return __uint_as_float(u << 16); }
__device__ __forceinline__ float bfu_hi(uint32 u) { return __uint_as_float(u & 0xffff0000u); }

// ====================== CSR construction (no global atomics) ======================
// Phase 1: per-partition bucket histogram.
__global__ __launch_bounds__(256) void hist_part(const int* __restrict__ ei, int E, int Etot,
                                                 int nbuck, int chunk, int* __restrict__ hist) {
    const int p = blockIdx.x;
    __shared__ int lh[MAXB];
    for (int i = threadIdx.x; i < nbuck; i += 256) lh[i] = 0;
    __syncthreads();
    const int beg = p * chunk;
    const int end = min(beg + chunk, Etot);
    for (int i = beg + threadIdx.x; i < end; i += 256) {
        int d = (i < E) ? ei[E + i] : i - E;
        atomicAdd(&lh[d >> BSHIFT], 1);
    }
    __syncthreads();
    for (int i = threadIdx.x; i < nbuck; i += 256) hist[(size_t)i * P_PART + p] = lh[i];
}

// Phase 2: exclusive scan of hist[b*P+p] (bucket-major), one 1024-thread block.
__global__ __launch_bounds__(1024) void hist_scan(int* __restrict__ hist, int M,
                                                  int* __restrict__ bbase, int nbuck, int Etot) {
    __shared__ int s[1024];
    const int t = threadIdx.x;
    const int S = (M + 1023) >> 10;
    const int beg = t * S, end = min(beg + S, M);
    int sum = 0;
    for (int i = beg; i < end; ++i) sum += hist[i];
    s[t] = sum;
    __syncthreads();
    for (int off = 1; off < 1024; off <<= 1) {
        int u = (t >= off) ? s[t - off] : 0;
        __syncthreads();
        s[t] += u;
        __syncthreads();
    }
    int acc = s[t] - sum;  // exclusive prefix of this thread's chunk
    for (int i = beg; i < end; ++i) { int v = hist[i]; hist[i] = acc; acc += v; }
    __syncthreads();
    for (int b = t; b < nbuck; b += 1024) bbase[b] = hist[(size_t)b * P_PART];
    if (t == 0) bbase[nbuck] = Etot;
}

// Phase 3: re-read edges; place into ebuf via LDS cursors (disjoint (b,p) ranges).
__global__ __launch_bounds__(256) void rank_scatter(const int* __restrict__ ei, int E, int Etot,
                                                    int nbuck, int chunk,
                                                    const int* __restrict__ hist,
                                                    uint32* __restrict__ ebuf) {
    const int p = blockIdx.x;
    __shared__ int cur[MAXB];
    for (int i = threadIdx.x; i < nbuck; i += 256) cur[i] = hist[(size_t)i * P_PART + p];
    __syncthreads();
    const int beg = p * chunk;
    const int end = min(beg + chunk, Etot);
    for (int i = beg + threadIdx.x; i < end; i += 256) {
        int s_, d_;
        if (i < E) { s_ = ei[i]; d_ = ei[E + i]; }
        else       { s_ = d_ = i - E; }
        int pos = atomicAdd(&cur[d_ >> BSHIFT], 1);
        ebuf[pos] = ((uint32)(d_ & ((1 << BSHIFT) - 1)) << 25) | (uint32)s_;
    }
}

// Phase 4: block per bucket. LDS node-degree histogram + 128-wide scan gives
// base[] directly (replaces the old deg_count + 3-kernel global scan), then
// places edges into the bucket's contiguous csr window (LDS cursors only).
__global__ __launch_bounds__(256) void bucket_place(
    const int* __restrict__ bbase, const uint32* __restrict__ ebuf, int N,
    int* __restrict__ base, int* __restrict__ csr_src) {
    const int bk = blockIdx.x;
    __shared__ int ldeg[1 << BSHIFT];
    __shared__ int sscan[1 << BSHIFT];
    __shared__ int lcur[1 << BSHIFT];
    const int t = threadIdx.x;
    if (t < (1 << BSHIFT)) { ldeg[t] = 0; lcur[t] = 0; }
    __syncthreads();
    const int beg = bbase[bk], end = bbase[bk + 1];
    for (int i = beg + t; i < end; i += 256) atomicAdd(&ldeg[ebuf[i] >> 25], 1);
    __syncthreads();
    if (t < 128) sscan[t] = ldeg[t];
    __syncthreads();
    for (int off = 1; off < 128; off <<= 1) {
        int v = 0;
        if (t < 128 && t >= off) v = sscan[t - off];
        __syncthreads();
        if (t < 128) sscan[t] += v;
        __syncthreads();
    }
    if (t < 128) {
        int node = (bk << BSHIFT) + t;
        if (node < N) base[node] = beg + sscan[t] - ldeg[t];
    }
    __syncthreads();
    for (int i = beg + t; i < end; i += 256) {
        uint32 pk = ebuf[i];
        int dl = (int)(pk >> 25);
        int s_ = (int)(pk & 0x1FFFFFFu);
        int pos = beg + (sscan[dl] - ldeg[dl]) + atomicAdd(&lcur[dl], 1);
        csr_src[pos] = s_;
    }
}

// gstart[g] = first node with batch[node] >= g (batch sorted); gstart[G] = N.
__global__ void graph_bounds(const int* __restrict__ batch, int N, int G,
                             int* __restrict__ gstart) {
    int g = blockIdx.x * blockDim.x + threadIdx.x;
    if (g > G) return;
    if (g == G) { gstart[G] = N; return; }
    int lo = 0, hi = N;
    while (lo < hi) { int mid = (lo + hi) >> 1; if (batch[mid] < g) lo = mid + 1; else hi = mid; }
    gstart[g] = lo;
}

// ================== pack W (+ attention columns) transposed, bf16 ==================
template <int OC, int C>
__global__ void pack_w(const float* __restrict__ W, const float* __restrict__ a_s,
                       const float* __restrict__ a_d, ushort16* __restrict__ wt) {
    const int col = blockIdx.x;
    const int k = threadIdx.x;  // 0..127
    float v = 0.f;
    if (col < OC) {
        v = W[k * OC + col];
    } else if (col < OC + 2) {
        int hh = col - OC;
        float s = 0.f;
        for (int c = 0; c < C; ++c) s += W[k * OC + hh * C + c] * a_s[hh * C + c];
        v = s;
    } else if (col < OC + 4) {
        int hh = col - OC - 2;
        float s = 0.f;
        for (int c = 0; c < C; ++c) s += W[k * OC + hh * C + c] * a_d[hh * C + c];
        v = s;
    }
    wt[(size_t)col * 128 + k] = f2bf(v);
}

// ==================== MFMA GEMM: h = x @ Wext (K=128) ====================
template <int OC, int NT, bool AF32>
__global__ __launch_bounds__(256) void gemm_mfma(
    const void* __restrict__ xin, const ushort16* __restrict__ wt,
    ushort16* __restrict__ h, float4* __restrict__ att, int N) {
    const int wave = threadIdx.x >> 6, lane = threadIdx.x & 63;
    const int tile = blockIdx.x * 4 + wave;
    if (tile * 16 >= N) return;
    const int m = lane & 15, quad = lane >> 4;
    const int node = tile * 16 + m;

    bf16x8 a[4];
    if (AF32) {
        const float* xr = (const float*)xin + (size_t)node * 128 + quad * 8;
#pragma unroll
        for (int c = 0; c < 4; ++c) {
            float4 u = *(const float4*)(xr + c * 32);
            float4 v = *(const float4*)(xr + c * 32 + 4);
            bf16x8 t;
            t[0] = (short)f2bf(u.x); t[1] = (short)f2bf(u.y);
            t[2] = (short)f2bf(u.z); t[3] = (short)f2bf(u.w);
            t[4] = (short)f2bf(v.x); t[5] = (short)f2bf(v.y);
            t[6] = (short)f2bf(v.z); t[7] = (short)f2bf(v.w);
            a[c] = t;
        }
    } else {
        const ushort16* xr = (const ushort16*)xin + (size_t)node * 128 + quad * 8;
#pragma unroll
        for (int c = 0; c < 4; ++c) a[c] = *(const bf16x8*)(xr + c * 32);
    }

    for (int t = 0; t < NT; ++t) {
        const ushort16* wr = wt + ((size_t)(t * 16 + m)) * 128 + quad * 8;
        bf16x8 b[4];
#pragma unroll
        for (int c = 0; c < 4; ++c) b[c] = *(const bf16x8*)(wr + c * 32);
        f32x4 acc = {0.f, 0.f, 0.f, 0.f};
#pragma unroll
        for (int c = 0; c < 4; ++c)
            acc = __builtin_amdgcn_mfma_f32_16x16x32_bf16(a[c], b[c], acc, 0, 0, 0);
        if (t * 16 < OC) {
#pragma unroll
            for (int r = 0; r < 4; ++r) {
                int nrow = tile * 16 + quad * 4 + r;
                h[(size_t)nrow * OC + t * 16 + m] = f2bf(acc[r]);
            }
        } else if (m < 4) {
#pragma unroll
            for (int r = 0; r < 4; ++r) {
                int nrow = tile * 16 + quad * 4 + r;
                ((float*)(att + nrow))[m] = acc[r];
            }
        }
    }
}

// ================= layer-1 gather: softmax-agg + bias + BN + ReLU -> bf16 =================
__global__ __launch_bounds__(256) void gat_gather1(
    const int* __restrict__ base, const int* __restrict__ csr_src, int Etot, int N,
    const ushort16* __restrict__ h, const float4* __restrict__ att,
    const float* __restrict__ b, const float* __restrict__ g, const float* __restrict__ be,
    const float* __restrict__ mu, const float* __restrict__ var,
    ushort16* __restrict__ outb) {
    const int node = __builtin_amdgcn_readfirstlane(blockIdx.x * 4 + (threadIdx.x >> 6));
    if (node >= N) return;
    const int t = threadIdx.x & 63;
    const int half = t >> 5;
    const int q = t & 31;      // channels 4q..4q+3
    const int hh = q >> 4;     // head
    const int beg = base[node];
    const int end = (node + 1 < N) ? base[node + 1] : Etot;
    const int deg = end - beg;
    const int nk = (deg - half + 1) >> 1;
    const int nkmax = (deg + 1) >> 1;
    const float4 adn = att[node];
    const float advh = hh ? adn.w : adn.z;

    float a0 = 0.f, a1 = 0.f, a2 = 0.f, a3 = 0.f, ssum = 0.f;
    constexpr int U = 4;
    for (int k = 0; k < nkmax; k += U) {
        int sidx[U];
        float msk[U];
#pragma unroll
        for (int j = 0; j < U; ++j) {
            int kk = k + j;
            bool ok = kk < nk;
            sidx[j] = csr_src[beg + (ok ? 2 * kk + half : 0)];
            msk[j] = ok ? 1.f : 0.f;
        }
        float4 av[U];
        uint2 hv[U];
#pragma unroll
        for (int j = 0; j < U; ++j) {
            av[j] = att[sidx[j]];
            hv[j] = *(const uint2*)(h + (size_t)sidx[j] * 128 + 4 * q);
        }
#pragma unroll
        for (int j = 0; j < U; ++j) {
            float ev = (hh ? av[j].y : av[j].x) + advh;
            ev = ev > 0.f ? ev : NEG_SLOPE * ev;
            float ex = __expf(ev) * msk[j];
            a0 += ex * bfu_lo(hv[j].x);
            a1 += ex * bfu_hi(hv[j].x);
            a2 += ex * bfu_lo(hv[j].y);
            a3 += ex * bfu_hi(hv[j].y);
            ssum += ex;
        }
    }
    a0 += __shfl_xor(a0, 32, 64);
    a1 += __shfl_xor(a1, 32, 64);
    a2 += __shfl_xor(a2, 32, 64);
    a3 += __shfl_xor(a3, 32, 64);
    ssum += __shfl_xor(ssum, 32, 64);
    if (half == 0) {
        const float inv = 1.f / (ssum + 1e-16f);
        const int c0 = 4 * q;
        float4 bb = *(const float4*)(b + c0);
        float4 gg = *(const float4*)(g + c0);
        float4 ee = *(const float4*)(be + c0);
        float4 mm = *(const float4*)(mu + c0);
        float4 vv = *(const float4*)(var + c0);
        float v0 = a0 * inv + bb.x, v1 = a1 * inv + bb.y;
        float v2 = a2 * inv + bb.z, v3 = a3 * inv + bb.w;
        v0 = fmaxf((v0 - mm.x) * rsqrtf(vv.x + BN_EPS) * gg.x + ee.x, 0.f);
        v1 = fmaxf((v1 - mm.y) * rsqrtf(vv.y + BN_EPS) * gg.y + ee.y, 0.f);
        v2 = fmaxf((v2 - mm.z) * rsqrtf(vv.z + BN_EPS) * gg.z + ee.z, 0.f);
        v3 = fmaxf((v3 - mm.w) * rsqrtf(vv.w + BN_EPS) * gg.w + ee.w, 0.f);
        uint2 r;
        r.x = (uint32)f2bf(v0) | ((uint32)f2bf(v1) << 16);
        r.y = (uint32)f2bf(v2) | ((uint32)f2bf(v3) << 16);
        *(uint2*)(outb + (size_t)node * 128 + c0) = r;
    }
}

// ====== layer-2 gather: softmax-agg + head-mean + bias + BN -> node_out ======
__global__ __launch_bounds__(256) void gat_gather2(
    const int* __restrict__ base, const int* __restrict__ csr_src, int Etot, int N,
    const ushort16* __restrict__ h2, const float4* __restrict__ att,
    const float* __restrict__ b2, const float* __restrict__ g, const float* __restrict__ be,
    const float* __restrict__ mu, const float* __restrict__ var,
    float* __restrict__ node_out) {
    const int node = __builtin_amdgcn_readfirstlane(blockIdx.x * 4 + (threadIdx.x >> 6));
    if (node >= N) return;
    const int t = threadIdx.x & 63;
    const int half = t >> 5;
    const int q = t & 31;      // channels 2q, 2q+1
    const int hh = q >> 4;     // head
    const int beg = base[node];
    const int end = (node + 1 < N) ? base[node + 1] : Etot;
    const int deg = end - beg;
    const int nk = (deg - half + 1) >> 1;
    const int nkmax = (deg + 1) >> 1;
    const float4 adn = att[node];
    const float advh = hh ? adn.w : adn.z;

    float accx = 0.f, accy = 0.f, ssum = 0.f;
    constexpr int U = 4;
    for (int k = 0; k < nkmax; k += U) {
        int sidx[U];
        float msk[U];
#pragma unroll
        for (int j = 0; j < U; ++j) {
            int kk = k + j;
            bool ok = kk < nk;
            sidx[j] = csr_src[beg + (ok ? 2 * kk + half : 0)];
            msk[j] = ok ? 1.f : 0.f;
        }
        float4 av[U];
        uint32 hv[U];
#pragma unroll
        for (int j = 0; j < U; ++j) {
            av[j] = att[sidx[j]];
            hv[j] = *(const uint32*)(h2 + (size_t)sidx[j] * 64 + 2 * q);
        }
#pragma unroll
        for (int j = 0; j < U; ++j) {
            float ev = (hh ? av[j].y : av[j].x) + advh;
            ev = ev > 0.f ? ev : NEG_SLOPE * ev;
            float ex = __expf(ev) * msk[j];
            accx += ex * bfu_lo(hv[j]);
            accy += ex * bfu_hi(hv[j]);
            ssum += ex;
        }
    }
    accx += __shfl_xor(accx, 32, 64);
    accy += __shfl_xor(accy, 32, 64);
    ssum += __shfl_xor(ssum, 32, 64);
    const float inv = 1.f / (ssum + 1e-16f);
    float v0 = accx * inv;
    float v1 = accy * inv;
    float p0 = __shfl(v0, (t & 15) + 16, 64);
    float p1 = __shfl(v1, (t & 15) + 16, 64);
    if (t < 16) {
        const int c0 = 2 * t;
        float m0 = 0.5f * (v0 + p0) + b2[c0];
        float m1 = 0.5f * (v1 + p1) + b2[c0 + 1];
        m0 = (m0 - mu[c0]) * rsqrtf(var[c0] + BN_EPS) * g[c0] + be[c0];
        m1 = (m1 - mu[c0 + 1]) * rsqrtf(var[c0 + 1] + BN_EPS) * g[c0 + 1] + be[c0 + 1];
        *(float2*)(node_out + (size_t)node * 32 + c0) = make_float2(m0, m1);
    }
}

// ============ block-per-graph: mean over nodes + log_softmax (32 classes) ============
__global__ __launch_bounds__(256) void pool_logsoftmax(
    const float* __restrict__ node_out, const int* __restrict__ gstart,
    float* __restrict__ out) {
    const int gidx = blockIdx.x;
    const int tid = threadIdx.x;
    const int c = tid & 31, r = tid >> 5;
    const int n0 = gstart[gidx], n1 = gstart[gidx + 1];
    float s = 0.f;
    for (int n = n0 + r; n < n1; n += 8) s += node_out[(size_t)n * 32 + c];
    __shared__ float red[8][32];
    red[r][c] = s;
    __syncthreads();
    if (r == 0) {
        float tot = red[0][c];
#pragma unroll
        for (int k = 1; k < 8; ++k) tot += red[k][c];
        float v = tot / fmaxf((float)(n1 - n0), 1.f);
        float m = v;
#pragma unroll
        for (int off = 16; off >= 1; off >>= 1) m = fmaxf(m, __shfl_xor(m, off, 64));
        float ex = __expf(v - m);
        float ssum = ex;
#pragma unroll
        for (int off = 16; off >= 1; off >>= 1) ssum += __shfl_xor(ssum, off, 64);
        out[gidx * 32 + c] = v - m - logf(ssum);
    }
}

extern "C" void kernel_launch(void* const* d_in, const int* in_sizes, int n_in,
                              void* d_out, int out_size, void* d_ws, size_t ws_size,
                              hipStream_t stream) {
    const float* x   = (const float*)d_in[0];
    const int* ei    = (const int*)d_in[1];
    const int* batch = (const int*)d_in[2];
    const float* W1  = (const float*)d_in[3];
    const float* as1 = (const float*)d_in[4];
    const float* ad1 = (const float*)d_in[5];
    const float* b1  = (const float*)d_in[6];
    const float* g1  = (const float*)d_in[7];
    const float* be1 = (const float*)d_in[8];
    const float* mu1 = (const float*)d_in[9];
    const float* vr1 = (const float*)d_in[10];
    const float* W2  = (const float*)d_in[11];
    const float* as2 = (const float*)d_in[12];
    const float* ad2 = (const float*)d_in[13];
    const float* b2  = (const float*)d_in[14];
    const float* g2  = (const float*)d_in[15];
    const float* be2 = (const float*)d_in[16];
    const float* mu2 = (const float*)d_in[17];
    const float* vr2 = (const float*)d_in[18];
    float* out = (float*)d_out;

    const int N = in_sizes[0] / 128;
    const int E = in_sizes[1] / 2;
    const int Etot = E + N;
    const int G = out_size / 32;
    const int nbuck = (N + (1 << BSHIFT) - 1) >> BSHIFT;
    const int chunk = (Etot + P_PART - 1) / P_PART;
    const int M = nbuck * P_PART;
    const int ntile = (N + 15) / 16;
    const int gemm_grid = (ntile + 3) / 4;

    // ---- workspace layout (units: floats; keep every region 16B-aligned) ----
    float* p = (float*)d_ws;
    size_t o = 0;
    auto al = [&]() { o = (o + 3) & ~(size_t)3; };
    ushort16* h1b   = (ushort16*)(p + o); o += (size_t)N * 64;  al();  // N*128 bf16
    ushort16* agg1b = (ushort16*)(p + o); o += (size_t)N * 64;  al();  // N*128 bf16
    ushort16* h2b   = (ushort16*)(p + o); o += (size_t)N * 32;  al();  // N*64 bf16
    float4* att1 = (float4*)(p + o); o += (size_t)N * 4;  al();
    float4* att2 = (float4*)(p + o); o += (size_t)N * 4;  al();
    float* nodeo = p + o; o += (size_t)N * 32; al();
    ushort16* wt1 = (ushort16*)(p + o); o += (size_t)144 * 64; al();   // 144x128 bf16
    ushort16* wt2 = (ushort16*)(p + o); o += (size_t)80 * 64;  al();   // 80x128 bf16
    int* csr_src = (int*)(p + o); o += (size_t)Etot; al();
    uint32* ebuf = (uint32*)(p + o); o += (size_t)Etot; al();
    int* base    = (int*)(p + o); o += (size_t)N;    al();
    int* hist    = (int*)(p + o); o += (size_t)M;    al();
    int* bbase   = (int*)(p + o); o += (size_t)nbuck + 4; al();
    int* gstart  = (int*)(p + o); o += (size_t)G + 4; al();
    // (no zero-init needed: every buffer is fully written before it is read)

    // ---- CSR build: histogram -> scan -> rank scatter -> place (+base) ----
    hist_part<<<P_PART, 256, 0, stream>>>(ei, E, Etot, nbuck, chunk, hist);
    hist_scan<<<1, 1024, 0, stream>>>(hist, M, bbase, nbuck, Etot);
    rank_scatter<<<P_PART, 256, 0, stream>>>(ei, E, Etot, nbuck, chunk, hist, ebuf);
    bucket_place<<<nbuck, 256, 0, stream>>>(bbase, ebuf, N, base, csr_src);
    // ---- graph bounds + weight pack ----
    graph_bounds<<<(G + 256) / 256, 256, 0, stream>>>(batch, N, G, gstart);
    pack_w<128, 64><<<144, 128, 0, stream>>>(W1, as1, ad1, wt1);
    pack_w<64, 32><<<80, 128, 0, stream>>>(W2, as2, ad2, wt2);

    // ---- layer 1 ----
    gemm_mfma<128, 9, true><<<gemm_grid, 256, 0, stream>>>(x, wt1, h1b, att1, N);
    gat_gather1<<<(N + 3) / 4, 256, 0, stream>>>(base, csr_src, Etot, N, h1b, att1,
                                                 b1, g1, be1, mu1, vr1, agg1b);
    // ---- layer 2 ----
    gemm_mfma<64, 5, false><<<gemm_grid, 256, 0, stream>>>(agg1b, wt2, h2b, att2, N);
    gat_gather2<<<(N + 3) / 4, 256, 0, stream>>>(base, csr_src, Etot, N, h2b, att2,
                                                 b2, g2, be2, mu2, vr2, nodeo);

    // ---- epilogue ----
    pool_logsoftmax<<<G, 256, 0, stream>>>(nodeo, gstart, out);
}

// Round 9
// 264.618 us; speedup vs baseline: 3.5136x; 1.5994x over previous
//
#include <hip/hip_runtime.h>
#include <hip/hip_bf16.h>

#define NEG_SLOPE 0.2f
#define BN_EPS 1e-5f
#define BSHIFT 7          // 128 nodes per bucket; src packed in low 25 bits (N < 2^25)
#define P_PART 256        // scatter partitions
#define MAXB 512          // max buckets supported (N <= 65536)

typedef unsigned int uint32;
typedef unsigned short ushort16;
typedef __attribute__((ext_vector_type(8))) short bf16x8;
typedef __attribute__((ext_vector_type(4))) float f32x4;

__device__ __forceinline__ ushort16 f2bf(float f) {
    uint32 u = __float_as_uint(f);
    u = (u + 0x7fff + ((u >> 16) & 1)) >> 16;  // round-to-nearest-even
    return (ushort16)u;
}
__device__ __forceinline__ float bfu_lo(uint32 u) { return __uint_as_float(u << 16); }
__device__ __forceinline__ float bfu_hi(uint32 u) { return __uint_as_float(u & 0xffff0000u); }

// ====================== CSR construction (no global atomics) ======================
// Phase 1: per-partition bucket histogram -> hist[b][p] (b-major).
__global__ __launch_bounds__(256) void hist_part(const int* __restrict__ ei, int E, int Etot,
                                                 int nbuck, int chunk, int* __restrict__ hist) {
    const int p = blockIdx.x;
    __shared__ int lh[MAXB];
    for (int i = threadIdx.x; i < nbuck; i += 256) lh[i] = 0;
    __syncthreads();
    const int beg = p * chunk;
    const int end = min(beg + chunk, Etot);
    for (int i = beg + threadIdx.x; i < end; i += 256) {
        int d = (i < E) ? ei[E + i] : i - E;
        atomicAdd(&lh[d >> BSHIFT], 1);
    }
    __syncthreads();
    for (int i = threadIdx.x; i < nbuck; i += 256) hist[(size_t)i * P_PART + p] = lh[i];
}

// Phase 2a: per-bucket exclusive scan over its 256 partition counts (block per bucket).
__global__ __launch_bounds__(P_PART) void row_scan(int* __restrict__ hist,
                                                   int* __restrict__ rowtot) {
    const int b = blockIdx.x;
    __shared__ int s[P_PART];
    const int t = threadIdx.x;
    int v = hist[(size_t)b * P_PART + t];
    s[t] = v;
    __syncthreads();
    for (int off = 1; off < P_PART; off <<= 1) {
        int u = (t >= off) ? s[t - off] : 0;
        __syncthreads();
        s[t] += u;
        __syncthreads();
    }
    hist[(size_t)b * P_PART + t] = s[t] - v;  // exclusive within bucket
    if (t == P_PART - 1) rowtot[b] = s[t];
}

// Phase 2b: exclusive scan of 391 bucket totals (single small block).
__global__ __launch_bounds__(512) void tot_scan(const int* __restrict__ rowtot,
                                                int* __restrict__ bbase, int nbuck, int Etot) {
    __shared__ int s[512];
    const int t = threadIdx.x;
    int v = (t < nbuck) ? rowtot[t] : 0;
    s[t] = v;
    __syncthreads();
    for (int off = 1; off < 512; off <<= 1) {
        int u = (t >= off) ? s[t - off] : 0;
        __syncthreads();
        s[t] += u;
        __syncthreads();
    }
    if (t < nbuck) bbase[t] = s[t] - v;
    if (t == 0) bbase[nbuck] = Etot;
}

// Phase 3: re-read edges; place into ebuf via LDS cursors (disjoint (b,p) ranges).
__global__ __launch_bounds__(256) void rank_scatter(const int* __restrict__ ei, int E, int Etot,
                                                    int nbuck, int chunk,
                                                    const int* __restrict__ hist,
                                                    const int* __restrict__ bbase,
                                                    uint32* __restrict__ ebuf) {
    const int p = blockIdx.x;
    __shared__ int cur[MAXB];
    for (int i = threadIdx.x; i < nbuck; i += 256)
        cur[i] = bbase[i] + hist[(size_t)i * P_PART + p];
    __syncthreads();
    const int beg = p * chunk;
    const int end = min(beg + chunk, Etot);
    for (int i = beg + threadIdx.x; i < end; i += 256) {
        int s_, d_;
        if (i < E) { s_ = ei[i]; d_ = ei[E + i]; }
        else       { s_ = d_ = i - E; }
        int pos = atomicAdd(&cur[d_ >> BSHIFT], 1);
        ebuf[pos] = ((uint32)(d_ & ((1 << BSHIFT) - 1)) << 25) | (uint32)s_;
    }
}

// Phase 4: block per bucket. LDS node-degree histogram + 128-wide scan gives
// base[] directly, then places edges into the bucket's csr window (LDS cursors).
__global__ __launch_bounds__(256) void bucket_place(
    const int* __restrict__ bbase, const uint32* __restrict__ ebuf, int N,
    int* __restrict__ base, int* __restrict__ csr_src) {
    const int bk = blockIdx.x;
    __shared__ int ldeg[1 << BSHIFT];
    __shared__ int sscan[1 << BSHIFT];
    __shared__ int lcur[1 << BSHIFT];
    const int t = threadIdx.x;
    if (t < (1 << BSHIFT)) { ldeg[t] = 0; lcur[t] = 0; }
    __syncthreads();
    const int beg = bbase[bk], end = bbase[bk + 1];
    for (int i = beg + t; i < end; i += 256) atomicAdd(&ldeg[ebuf[i] >> 25], 1);
    __syncthreads();
    if (t < 128) sscan[t] = ldeg[t];
    __syncthreads();
    for (int off = 1; off < 128; off <<= 1) {
        int v = 0;
        if (t < 128 && t >= off) v = sscan[t - off];
        __syncthreads();
        if (t < 128) sscan[t] += v;
        __syncthreads();
    }
    if (t < 128) {
        int node = (bk << BSHIFT) + t;
        if (node < N) base[node] = beg + sscan[t] - ldeg[t];
    }
    __syncthreads();
    for (int i = beg + t; i < end; i += 256) {
        uint32 pk = ebuf[i];
        int dl = (int)(pk >> 25);
        int s_ = (int)(pk & 0x1FFFFFFu);
        int pos = beg + (sscan[dl] - ldeg[dl]) + atomicAdd(&lcur[dl], 1);
        csr_src[pos] = s_;
    }
}

// gstart[g] = first node with batch[node] >= g (batch sorted); gstart[G] = N.
__global__ void graph_bounds(const int* __restrict__ batch, int N, int G,
                             int* __restrict__ gstart) {
    int g = blockIdx.x * blockDim.x + threadIdx.x;
    if (g > G) return;
    if (g == G) { gstart[G] = N; return; }
    int lo = 0, hi = N;
    while (lo < hi) { int mid = (lo + hi) >> 1; if (batch[mid] < g) lo = mid + 1; else hi = mid; }
    gstart[g] = lo;
}

// ================== pack W (+ attention columns) transposed, bf16 ==================
template <int OC, int C>
__global__ void pack_w(const float* __restrict__ W, const float* __restrict__ a_s,
                       const float* __restrict__ a_d, ushort16* __restrict__ wt) {
    const int col = blockIdx.x;
    const int k = threadIdx.x;  // 0..127
    float v = 0.f;
    if (col < OC) {
        v = W[k * OC + col];
    } else if (col < OC + 2) {
        int hh = col - OC;
        float s = 0.f;
        for (int c = 0; c < C; ++c) s += W[k * OC + hh * C + c] * a_s[hh * C + c];
        v = s;
    } else if (col < OC + 4) {
        int hh = col - OC - 2;
        float s = 0.f;
        for (int c = 0; c < C; ++c) s += W[k * OC + hh * C + c] * a_d[hh * C + c];
        v = s;
    }
    wt[(size_t)col * 128 + k] = f2bf(v);
}

// ==================== MFMA GEMM: h = x @ Wext (K=128) ====================
template <int OC, int NT, bool AF32>
__global__ __launch_bounds__(256) void gemm_mfma(
    const void* __restrict__ xin, const ushort16* __restrict__ wt,
    ushort16* __restrict__ h, float4* __restrict__ att, int N) {
    const int wave = threadIdx.x >> 6, lane = threadIdx.x & 63;
    const int tile = blockIdx.x * 4 + wave;
    if (tile * 16 >= N) return;
    const int m = lane & 15, quad = lane >> 4;
    const int node = tile * 16 + m;

    bf16x8 a[4];
    if (AF32) {
        const float* xr = (const float*)xin + (size_t)node * 128 + quad * 8;
#pragma unroll
        for (int c = 0; c < 4; ++c) {
            float4 u = *(const float4*)(xr + c * 32);
            float4 v = *(const float4*)(xr + c * 32 + 4);
            bf16x8 t;
            t[0] = (short)f2bf(u.x); t[1] = (short)f2bf(u.y);
            t[2] = (short)f2bf(u.z); t[3] = (short)f2bf(u.w);
            t[4] = (short)f2bf(v.x); t[5] = (short)f2bf(v.y);
            t[6] = (short)f2bf(v.z); t[7] = (short)f2bf(v.w);
            a[c] = t;
        }
    } else {
        const ushort16* xr = (const ushort16*)xin + (size_t)node * 128 + quad * 8;
#pragma unroll
        for (int c = 0; c < 4; ++c) a[c] = *(const bf16x8*)(xr + c * 32);
    }

    for (int t = 0; t < NT; ++t) {
        const ushort16* wr = wt + ((size_t)(t * 16 + m)) * 128 + quad * 8;
        bf16x8 b[4];
#pragma unroll
        for (int c = 0; c < 4; ++c) b[c] = *(const bf16x8*)(wr + c * 32);
        f32x4 acc = {0.f, 0.f, 0.f, 0.f};
#pragma unroll
        for (int c = 0; c < 4; ++c)
            acc = __builtin_amdgcn_mfma_f32_16x16x32_bf16(a[c], b[c], acc, 0, 0, 0);
        if (t * 16 < OC) {
#pragma unroll
            for (int r = 0; r < 4; ++r) {
                int nrow = tile * 16 + quad * 4 + r;
                h[(size_t)nrow * OC + t * 16 + m] = f2bf(acc[r]);
            }
        } else if (m < 4) {
#pragma unroll
            for (int r = 0; r < 4; ++r) {
                int nrow = tile * 16 + quad * 4 + r;
                ((float*)(att + nrow))[m] = acc[r];
            }
        }
    }
}

// ================= layer-1 gather: softmax-agg + bias + BN + ReLU -> bf16 =================
__global__ __launch_bounds__(256) void gat_gather1(
    const int* __restrict__ base, const int* __restrict__ csr_src, int Etot, int N,
    const ushort16* __restrict__ h, const float4* __restrict__ att,
    const float* __restrict__ b, const float* __restrict__ g, const float* __restrict__ be,
    const float* __restrict__ mu, const float* __restrict__ var,
    ushort16* __restrict__ outb) {
    const int node = __builtin_amdgcn_readfirstlane(blockIdx.x * 4 + (threadIdx.x >> 6));
    if (node >= N) return;
    const int t = threadIdx.x & 63;
    const int half = t >> 5;
    const int q = t & 31;      // channels 4q..4q+3
    const int hh = q >> 4;     // head
    const int beg = base[node];
    const int end = (node + 1 < N) ? base[node + 1] : Etot;
    const int deg = end - beg;
    const int nk = (deg - half + 1) >> 1;
    const int nkmax = (deg + 1) >> 1;
    const float4 adn = att[node];
    const float advh = hh ? adn.w : adn.z;

    float a0 = 0.f, a1 = 0.f, a2 = 0.f, a3 = 0.f, ssum = 0.f;
    constexpr int U = 4;
    for (int k = 0; k < nkmax; k += U) {
        int sidx[U];
        float msk[U];
#pragma unroll
        for (int j = 0; j < U; ++j) {
            int kk = k + j;
            bool ok = kk < nk;
            sidx[j] = csr_src[beg + (ok ? 2 * kk + half : 0)];
            msk[j] = ok ? 1.f : 0.f;
        }
        float4 av[U];
        uint2 hv[U];
#pragma unroll
        for (int j = 0; j < U; ++j) {
            av[j] = att[sidx[j]];
            hv[j] = *(const uint2*)(h + (size_t)sidx[j] * 128 + 4 * q);
        }
#pragma unroll
        for (int j = 0; j < U; ++j) {
            float ev = (hh ? av[j].y : av[j].x) + advh;
            ev = ev > 0.f ? ev : NEG_SLOPE * ev;
            float ex = __expf(ev) * msk[j];
            a0 += ex * bfu_lo(hv[j].x);
            a1 += ex * bfu_hi(hv[j].x);
            a2 += ex * bfu_lo(hv[j].y);
            a3 += ex * bfu_hi(hv[j].y);
            ssum += ex;
        }
    }
    a0 += __shfl_xor(a0, 32, 64);
    a1 += __shfl_xor(a1, 32, 64);
    a2 += __shfl_xor(a2, 32, 64);
    a3 += __shfl_xor(a3, 32, 64);
    ssum += __shfl_xor(ssum, 32, 64);
    if (half == 0) {
        const float inv = 1.f / (ssum + 1e-16f);
        const int c0 = 4 * q;
        float4 bb = *(const float4*)(b + c0);
        float4 gg = *(const float4*)(g + c0);
        float4 ee = *(const float4*)(be + c0);
        float4 mm = *(const float4*)(mu + c0);
        float4 vv = *(const float4*)(var + c0);
        float v0 = a0 * inv + bb.x, v1 = a1 * inv + bb.y;
        float v2 = a2 * inv + bb.z, v3 = a3 * inv + bb.w;
        v0 = fmaxf((v0 - mm.x) * rsqrtf(vv.x + BN_EPS) * gg.x + ee.x, 0.f);
        v1 = fmaxf((v1 - mm.y) * rsqrtf(vv.y + BN_EPS) * gg.y + ee.y, 0.f);
        v2 = fmaxf((v2 - mm.z) * rsqrtf(vv.z + BN_EPS) * gg.z + ee.z, 0.f);
        v3 = fmaxf((v3 - mm.w) * rsqrtf(vv.w + BN_EPS) * gg.w + ee.w, 0.f);
        uint2 r;
        r.x = (uint32)f2bf(v0) | ((uint32)f2bf(v1) << 16);
        r.y = (uint32)f2bf(v2) | ((uint32)f2bf(v3) << 16);
        *(uint2*)(outb + (size_t)node * 128 + c0) = r;
    }
}

// ====== layer-2 gather: softmax-agg + head-mean + bias + BN -> node_out ======
__global__ __launch_bounds__(256) void gat_gather2(
    const int* __restrict__ base, const int* __restrict__ csr_src, int Etot, int N,
    const ushort16* __restrict__ h2, const float4* __restrict__ att,
    const float* __restrict__ b2, const float* __restrict__ g, const float* __restrict__ be,
    const float* __restrict__ mu, const float* __restrict__ var,
    float* __restrict__ node_out) {
    const int node = __builtin_amdgcn_readfirstlane(blockIdx.x * 4 + (threadIdx.x >> 6));
    if (node >= N) return;
    const int t = threadIdx.x & 63;
    const int half = t >> 5;
    const int q = t & 31;      // channels 2q, 2q+1
    const int hh = q >> 4;     // head
    const int beg = base[node];
    const int end = (node + 1 < N) ? base[node + 1] : Etot;
    const int deg = end - beg;
    const int nk = (deg - half + 1) >> 1;
    const int nkmax = (deg + 1) >> 1;
    const float4 adn = att[node];
    const float advh = hh ? adn.w : adn.z;

    float accx = 0.f, accy = 0.f, ssum = 0.f;
    constexpr int U = 4;
    for (int k = 0; k < nkmax; k += U) {
        int sidx[U];
        float msk[U];
#pragma unroll
        for (int j = 0; j < U; ++j) {
            int kk = k + j;
            bool ok = kk < nk;
            sidx[j] = csr_src[beg + (ok ? 2 * kk + half : 0)];
            msk[j] = ok ? 1.f : 0.f;
        }
        float4 av[U];
        uint32 hv[U];
#pragma unroll
        for (int j = 0; j < U; ++j) {
            av[j] = att[sidx[j]];
            hv[j] = *(const uint32*)(h2 + (size_t)sidx[j] * 64 + 2 * q);
        }
#pragma unroll
        for (int j = 0; j < U; ++j) {
            float ev = (hh ? av[j].y : av[j].x) + advh;
            ev = ev > 0.f ? ev : NEG_SLOPE * ev;
            float ex = __expf(ev) * msk[j];
            accx += ex * bfu_lo(hv[j]);
            accy += ex * bfu_hi(hv[j]);
            ssum += ex;
        }
    }
    accx += __shfl_xor(accx, 32, 64);
    accy += __shfl_xor(accy, 32, 64);
    ssum += __shfl_xor(ssum, 32, 64);
    const float inv = 1.f / (ssum + 1e-16f);
    float v0 = accx * inv;
    float v1 = accy * inv;
    float p0 = __shfl(v0, (t & 15) + 16, 64);
    float p1 = __shfl(v1, (t & 15) + 16, 64);
    if (t < 16) {
        const int c0 = 2 * t;
        float m0 = 0.5f * (v0 + p0) + b2[c0];
        float m1 = 0.5f * (v1 + p1) + b2[c0 + 1];
        m0 = (m0 - mu[c0]) * rsqrtf(var[c0] + BN_EPS) * g[c0] + be[c0];
        m1 = (m1 - mu[c0 + 1]) * rsqrtf(var[c0 + 1] + BN_EPS) * g[c0 + 1] + be[c0 + 1];
        *(float2*)(node_out + (size_t)node * 32 + c0) = make_float2(m0, m1);
    }
}

// ============ block-per-graph: mean over nodes + log_softmax (32 classes) ============
__global__ __launch_bounds__(256) void pool_logsoftmax(
    const float* __restrict__ node_out, const int* __restrict__ gstart,
    float* __restrict__ out) {
    const int gidx = blockIdx.x;
    const int tid = threadIdx.x;
    const int c = tid & 31, r = tid >> 5;
    const int n0 = gstart[gidx], n1 = gstart[gidx + 1];
    float s = 0.f;
    for (int n = n0 + r; n < n1; n += 8) s += node_out[(size_t)n * 32 + c];
    __shared__ float red[8][32];
    red[r][c] = s;
    __syncthreads();
    if (r == 0) {
        float tot = red[0][c];
#pragma unroll
        for (int k = 1; k < 8; ++k) tot += red[k][c];
        float v = tot / fmaxf((float)(n1 - n0), 1.f);
        float m = v;
#pragma unroll
        for (int off = 16; off >= 1; off >>= 1) m = fmaxf(m, __shfl_xor(m, off, 64));
        float ex = __expf(v - m);
        float ssum = ex;
#pragma unroll
        for (int off = 16; off >= 1; off >>= 1) ssum += __shfl_xor(ssum, off, 64);
        out[gidx * 32 + c] = v - m - logf(ssum);
    }
}

extern "C" void kernel_launch(void* const* d_in, const int* in_sizes, int n_in,
                              void* d_out, int out_size, void* d_ws, size_t ws_size,
                              hipStream_t stream) {
    const float* x   = (const float*)d_in[0];
    const int* ei    = (const int*)d_in[1];
    const int* batch = (const int*)d_in[2];
    const float* W1  = (const float*)d_in[3];
    const float* as1 = (const float*)d_in[4];
    const float* ad1 = (const float*)d_in[5];
    const float* b1  = (const float*)d_in[6];
    const float* g1  = (const float*)d_in[7];
    const float* be1 = (const float*)d_in[8];
    const float* mu1 = (const float*)d_in[9];
    const float* vr1 = (const float*)d_in[10];
    const float* W2  = (const float*)d_in[11];
    const float* as2 = (const float*)d_in[12];
    const float* ad2 = (const float*)d_in[13];
    const float* b2  = (const float*)d_in[14];
    const float* g2  = (const float*)d_in[15];
    const float* be2 = (const float*)d_in[16];
    const float* mu2 = (const float*)d_in[17];
    const float* vr2 = (const float*)d_in[18];
    float* out = (float*)d_out;

    const int N = in_sizes[0] / 128;
    const int E = in_sizes[1] / 2;
    const int Etot = E + N;
    const int G = out_size / 32;
    const int nbuck = (N + (1 << BSHIFT) - 1) >> BSHIFT;
    const int chunk = (Etot + P_PART - 1) / P_PART;
    const int M = nbuck * P_PART;
    const int ntile = (N + 15) / 16;
    const int gemm_grid = (ntile + 3) / 4;

    // ---- workspace layout (units: floats; keep every region 16B-aligned) ----
    float* p = (float*)d_ws;
    size_t o = 0;
    auto al = [&]() { o = (o + 3) & ~(size_t)3; };
    ushort16* h1b   = (ushort16*)(p + o); o += (size_t)N * 64;  al();  // N*128 bf16
    ushort16* agg1b = (ushort16*)(p + o); o += (size_t)N * 64;  al();  // N*128 bf16
    ushort16* h2b   = (ushort16*)(p + o); o += (size_t)N * 32;  al();  // N*64 bf16
    float4* att1 = (float4*)(p + o); o += (size_t)N * 4;  al();
    float4* att2 = (float4*)(p + o); o += (size_t)N * 4;  al();
    float* nodeo = p + o; o += (size_t)N * 32; al();
    ushort16* wt1 = (ushort16*)(p + o); o += (size_t)144 * 64; al();   // 144x128 bf16
    ushort16* wt2 = (ushort16*)(p + o); o += (size_t)80 * 64;  al();   // 80x128 bf16
    int* csr_src = (int*)(p + o); o += (size_t)Etot; al();
    uint32* ebuf = (uint32*)(p + o); o += (size_t)Etot; al();
    int* base    = (int*)(p + o); o += (size_t)N;    al();
    int* hist    = (int*)(p + o); o += (size_t)M;    al();
    int* rowtot  = (int*)(p + o); o += (size_t)nbuck + 4; al();
    int* bbase   = (int*)(p + o); o += (size_t)nbuck + 4; al();
    int* gstart  = (int*)(p + o); o += (size_t)G + 4; al();
    // (no zero-init needed: every buffer is fully written before it is read)

    // ---- CSR build: histogram -> row scan -> total scan -> rank scatter -> place ----
    hist_part<<<P_PART, 256, 0, stream>>>(ei, E, Etot, nbuck, chunk, hist);
    row_scan<<<nbuck, P_PART, 0, stream>>>(hist, rowtot);
    tot_scan<<<1, 512, 0, stream>>>(rowtot, bbase, nbuck, Etot);
    rank_scatter<<<P_PART, 256, 0, stream>>>(ei, E, Etot, nbuck, chunk, hist, bbase, ebuf);
    bucket_place<<<nbuck, 256, 0, stream>>>(bbase, ebuf, N, base, csr_src);
    // ---- graph bounds + weight pack ----
    graph_bounds<<<(G + 256) / 256, 256, 0, stream>>>(batch, N, G, gstart);
    pack_w<128, 64><<<144, 128, 0, stream>>>(W1, as1, ad1, wt1);
    pack_w<64, 32><<<80, 128, 0, stream>>>(W2, as2, ad2, wt2);

    // ---- layer 1 ----
    gemm_mfma<128, 9, true><<<gemm_grid, 256, 0, stream>>>(x, wt1, h1b, att1, N);
    gat_gather1<<<(N + 3) / 4, 256, 0, stream>>>(base, csr_src, Etot, N, h1b, att1,
                                                 b1, g1, be1, mu1, vr1, agg1b);
    // ---- layer 2 ----
    gemm_mfma<64, 5, false><<<gemm_grid, 256, 0, stream>>>(agg1b, wt2, h2b, att2, N);
    gat_gather2<<<(N + 3) / 4, 256, 0, stream>>>(base, csr_src, Etot, N, h2b, att2,
                                                 b2, g2, be2, mu2, vr2, nodeo);

    // ---- epilogue ----
    pool_logsoftmax<<<G, 256, 0, stream>>>(nodeo, gstart, out);
}

// Round 10
// 257.749 us; speedup vs baseline: 3.6073x; 1.0266x over previous
//
#include <hip/hip_runtime.h>
#include <hip/hip_bf16.h>

#define NEG_SLOPE 0.2f
#define BN_EPS 1e-5f
#define BSHIFT 7          // 128 nodes per bucket; src packed in low 25 bits (N < 2^25)
#define P_PART 256        // scatter partitions
#define MAXB 512          // max buckets supported (N <= 65536)

typedef unsigned int uint32;
typedef unsigned short ushort16;
typedef __attribute__((ext_vector_type(8))) short bf16x8;
typedef __attribute__((ext_vector_type(4))) float f32x4;

__device__ __forceinline__ ushort16 f2bf(float f) {
    uint32 u = __float_as_uint(f);
    u = (u + 0x7fff + ((u >> 16) & 1)) >> 16;  // round-to-nearest-even
    return (ushort16)u;
}
__device__ __forceinline__ float bfu_lo(uint32 u) { return __uint_as_float(u << 16); }
__device__ __forceinline__ float bfu_hi(uint32 u) { return __uint_as_float(u & 0xffff0000u); }

// ====================== CSR construction (no global atomics) ======================
// Phase 1: per-partition bucket histogram -> hist[b][p] (b-major).
__global__ __launch_bounds__(256) void hist_part(const int* __restrict__ ei, int E, int Etot,
                                                 int nbuck, int chunk, int* __restrict__ hist) {
    const int p = blockIdx.x;
    __shared__ int lh[MAXB];
    for (int i = threadIdx.x; i < nbuck; i += 256) lh[i] = 0;
    __syncthreads();
    const int beg = p * chunk;
    const int end = min(beg + chunk, Etot);
    for (int i = beg + threadIdx.x; i < end; i += 256) {
        int d = (i < E) ? ei[E + i] : i - E;
        atomicAdd(&lh[d >> BSHIFT], 1);
    }
    __syncthreads();
    for (int i = threadIdx.x; i < nbuck; i += 256) hist[(size_t)i * P_PART + p] = lh[i];
}

// Phase 2a: per-bucket exclusive scan over its 256 partition counts (block per bucket).
__global__ __launch_bounds__(P_PART) void row_scan(int* __restrict__ hist,
                                                   int* __restrict__ rowtot) {
    const int b = blockIdx.x;
    __shared__ int s[P_PART];
    const int t = threadIdx.x;
    int v = hist[(size_t)b * P_PART + t];
    s[t] = v;
    __syncthreads();
    for (int off = 1; off < P_PART; off <<= 1) {
        int u = (t >= off) ? s[t - off] : 0;
        __syncthreads();
        s[t] += u;
        __syncthreads();
    }
    hist[(size_t)b * P_PART + t] = s[t] - v;  // exclusive within bucket
    if (t == P_PART - 1) rowtot[b] = s[t];
}

// Phase 2b: exclusive scan of bucket totals (single small block).
__global__ __launch_bounds__(512) void tot_scan(const int* __restrict__ rowtot,
                                                int* __restrict__ bbase, int nbuck, int Etot) {
    __shared__ int s[512];
    const int t = threadIdx.x;
    int v = (t < nbuck) ? rowtot[t] : 0;
    s[t] = v;
    __syncthreads();
    for (int off = 1; off < 512; off <<= 1) {
        int u = (t >= off) ? s[t - off] : 0;
        __syncthreads();
        s[t] += u;
        __syncthreads();
    }
    if (t < nbuck) bbase[t] = s[t] - v;
    if (t == 0) bbase[nbuck] = Etot;
}

// Phase 3: re-read edges; place into ebuf via LDS cursors (disjoint (b,p) ranges).
__global__ __launch_bounds__(256) void rank_scatter(const int* __restrict__ ei, int E, int Etot,
                                                    int nbuck, int chunk,
                                                    const int* __restrict__ hist,
                                                    const int* __restrict__ bbase,
                                                    uint32* __restrict__ ebuf) {
    const int p = blockIdx.x;
    __shared__ int cur[MAXB];
    for (int i = threadIdx.x; i < nbuck; i += 256)
        cur[i] = bbase[i] + hist[(size_t)i * P_PART + p];
    __syncthreads();
    const int beg = p * chunk;
    const int end = min(beg + chunk, Etot);
    for (int i = beg + threadIdx.x; i < end; i += 256) {
        int s_, d_;
        if (i < E) { s_ = ei[i]; d_ = ei[E + i]; }
        else       { s_ = d_ = i - E; }
        int pos = atomicAdd(&cur[d_ >> BSHIFT], 1);
        ebuf[pos] = ((uint32)(d_ & ((1 << BSHIFT) - 1)) << 25) | (uint32)s_;
    }
}

// Phase 4: block per bucket. LDS node-degree histogram + 128-wide scan gives
// base[] directly, then places edges into the bucket's csr window (LDS cursors).
__global__ __launch_bounds__(256) void bucket_place(
    const int* __restrict__ bbase, const uint32* __restrict__ ebuf, int N,
    int* __restrict__ base, int* __restrict__ csr_src) {
    const int bk = blockIdx.x;
    __shared__ int ldeg[1 << BSHIFT];
    __shared__ int sscan[1 << BSHIFT];
    __shared__ int lcur[1 << BSHIFT];
    const int t = threadIdx.x;
    if (t < (1 << BSHIFT)) { ldeg[t] = 0; lcur[t] = 0; }
    __syncthreads();
    const int beg = bbase[bk], end = bbase[bk + 1];
    for (int i = beg + t; i < end; i += 256) atomicAdd(&ldeg[ebuf[i] >> 25], 1);
    __syncthreads();
    if (t < 128) sscan[t] = ldeg[t];
    __syncthreads();
    for (int off = 1; off < 128; off <<= 1) {
        int v = 0;
        if (t < 128 && t >= off) v = sscan[t - off];
        __syncthreads();
        if (t < 128) sscan[t] += v;
        __syncthreads();
    }
    if (t < 128) {
        int node = (bk << BSHIFT) + t;
        if (node < N) base[node] = beg + sscan[t] - ldeg[t];
    }
    __syncthreads();
    for (int i = beg + t; i < end; i += 256) {
        uint32 pk = ebuf[i];
        int dl = (int)(pk >> 25);
        int s_ = (int)(pk & 0x1FFFFFFu);
        int pos = beg + (sscan[dl] - ldeg[dl]) + atomicAdd(&lcur[dl], 1);
        csr_src[pos] = s_;
    }
}

// gstart[g] = first node with batch[node] >= g (batch sorted); gstart[G] = N.
__global__ void graph_bounds(const int* __restrict__ batch, int N, int G,
                             int* __restrict__ gstart) {
    int g = blockIdx.x * blockDim.x + threadIdx.x;
    if (g > G) return;
    if (g == G) { gstart[G] = N; return; }
    int lo = 0, hi = N;
    while (lo < hi) { int mid = (lo + hi) >> 1; if (batch[mid] < g) lo = mid + 1; else hi = mid; }
    gstart[g] = lo;
}

// ================== pack W (+ attention columns) transposed, bf16 ==================
template <int OC, int C>
__global__ void pack_w(const float* __restrict__ W, const float* __restrict__ a_s,
                       const float* __restrict__ a_d, ushort16* __restrict__ wt) {
    const int col = blockIdx.x;
    const int k = threadIdx.x;  // 0..127
    float v = 0.f;
    if (col < OC) {
        v = W[k * OC + col];
    } else if (col < OC + 2) {
        int hh = col - OC;
        float s = 0.f;
        for (int c = 0; c < C; ++c) s += W[k * OC + hh * C + c] * a_s[hh * C + c];
        v = s;
    } else if (col < OC + 4) {
        int hh = col - OC - 2;
        float s = 0.f;
        for (int c = 0; c < C; ++c) s += W[k * OC + hh * C + c] * a_d[hh * C + c];
        v = s;
    }
    wt[(size_t)col * 128 + k] = f2bf(v);
}

// ==================== MFMA GEMM: h = x @ Wext (K=128) ====================
// att = (as_h0, as_h1, ad_h0, ad_h1) fp32; asc = (as_h0, as_h1) duplicate for gathers.
template <int OC, int NT, bool AF32>
__global__ __launch_bounds__(256) void gemm_mfma(
    const void* __restrict__ xin, const ushort16* __restrict__ wt,
    ushort16* __restrict__ h, float4* __restrict__ att, float2* __restrict__ asc, int N) {
    const int wave = threadIdx.x >> 6, lane = threadIdx.x & 63;
    const int tile = blockIdx.x * 4 + wave;
    if (tile * 16 >= N) return;
    const int m = lane & 15, quad = lane >> 4;
    const int node = tile * 16 + m;

    bf16x8 a[4];
    if (AF32) {
        const float* xr = (const float*)xin + (size_t)node * 128 + quad * 8;
#pragma unroll
        for (int c = 0; c < 4; ++c) {
            float4 u = *(const float4*)(xr + c * 32);
            float4 v = *(const float4*)(xr + c * 32 + 4);
            bf16x8 t;
            t[0] = (short)f2bf(u.x); t[1] = (short)f2bf(u.y);
            t[2] = (short)f2bf(u.z); t[3] = (short)f2bf(u.w);
            t[4] = (short)f2bf(v.x); t[5] = (short)f2bf(v.y);
            t[6] = (short)f2bf(v.z); t[7] = (short)f2bf(v.w);
            a[c] = t;
        }
    } else {
        const ushort16* xr = (const ushort16*)xin + (size_t)node * 128 + quad * 8;
#pragma unroll
        for (int c = 0; c < 4; ++c) a[c] = *(const bf16x8*)(xr + c * 32);
    }

    for (int t = 0; t < NT; ++t) {
        const ushort16* wr = wt + ((size_t)(t * 16 + m)) * 128 + quad * 8;
        bf16x8 b[4];
#pragma unroll
        for (int c = 0; c < 4; ++c) b[c] = *(const bf16x8*)(wr + c * 32);
        f32x4 acc = {0.f, 0.f, 0.f, 0.f};
#pragma unroll
        for (int c = 0; c < 4; ++c)
            acc = __builtin_amdgcn_mfma_f32_16x16x32_bf16(a[c], b[c], acc, 0, 0, 0);
        if (t * 16 < OC) {
#pragma unroll
            for (int r = 0; r < 4; ++r) {
                int nrow = tile * 16 + quad * 4 + r;
                h[(size_t)nrow * OC + t * 16 + m] = f2bf(acc[r]);
            }
        } else if (m < 4) {
#pragma unroll
            for (int r = 0; r < 4; ++r) {
                int nrow = tile * 16 + quad * 4 + r;
                ((float*)(att + nrow))[m] = acc[r];
                if (m < 2) ((float*)(asc + nrow))[m] = acc[r];
            }
        }
    }
}

// ================= layer-1 gather: softmax-agg + bias + BN + ReLU -> bf16 =================
// One wave per node; 16 lanes per edge (4 edge streams/wave), 8 channels/lane (uint4).
__global__ __launch_bounds__(256) void gat_gather1(
    const int* __restrict__ base, const int* __restrict__ csr_src, int Etot, int N,
    const ushort16* __restrict__ h, const float4* __restrict__ att,
    const float2* __restrict__ asc,
    const float* __restrict__ b, const float* __restrict__ g, const float* __restrict__ be,
    const float* __restrict__ mu, const float* __restrict__ var,
    ushort16* __restrict__ outb) {
    const int node = __builtin_amdgcn_readfirstlane(blockIdx.x * 4 + (threadIdx.x >> 6));
    if (node >= N) return;
    const int t = threadIdx.x & 63;
    const int sub = t >> 4;    // edge stream 0..3
    const int q = t & 15;      // channels 8q..8q+7
    const int hh = q >> 3;     // head
    const int beg = base[node];
    const int end = (node + 1 < N) ? base[node + 1] : Etot;
    const int deg = end - beg;
    const int nk = (deg - sub + 3) >> 2;   // slots for this stream
    const int nkmax = (deg + 3) >> 2;
    const float4 adn = att[node];
    const float advh = hh ? adn.w : adn.z;

    float a0 = 0.f, a1 = 0.f, a2 = 0.f, a3 = 0.f;
    float a4 = 0.f, a5 = 0.f, a6 = 0.f, a7 = 0.f, ssum = 0.f;
    constexpr int U = 4;
    for (int k = 0; k < nkmax; k += U) {
        int sidx[U];
        float msk[U];
#pragma unroll
        for (int j = 0; j < U; ++j) {
            int kk = k + j;
            bool ok = kk < nk;
            sidx[j] = csr_src[beg + (ok ? 4 * kk + sub : 0)];
            msk[j] = ok ? 1.f : 0.f;
        }
        float2 av[U];
        uint4 hv[U];
#pragma unroll
        for (int j = 0; j < U; ++j) {
            av[j] = asc[sidx[j]];
            hv[j] = *(const uint4*)(h + (size_t)sidx[j] * 128 + 8 * q);
        }
#pragma unroll
        for (int j = 0; j < U; ++j) {
            float ev = (hh ? av[j].y : av[j].x) + advh;
            ev = ev > 0.f ? ev : NEG_SLOPE * ev;
            float ex = __expf(ev) * msk[j];
            a0 += ex * bfu_lo(hv[j].x);
            a1 += ex * bfu_hi(hv[j].x);
            a2 += ex * bfu_lo(hv[j].y);
            a3 += ex * bfu_hi(hv[j].y);
            a4 += ex * bfu_lo(hv[j].z);
            a5 += ex * bfu_hi(hv[j].z);
            a6 += ex * bfu_lo(hv[j].w);
            a7 += ex * bfu_hi(hv[j].w);
            ssum += ex;
        }
    }
    // reduce the 4 edge streams (lanes differing in bits 4,5 hold same channels)
#pragma unroll
    for (int off = 16; off <= 32; off <<= 1) {
        a0 += __shfl_xor(a0, off, 64);
        a1 += __shfl_xor(a1, off, 64);
        a2 += __shfl_xor(a2, off, 64);
        a3 += __shfl_xor(a3, off, 64);
        a4 += __shfl_xor(a4, off, 64);
        a5 += __shfl_xor(a5, off, 64);
        a6 += __shfl_xor(a6, off, 64);
        a7 += __shfl_xor(a7, off, 64);
        ssum += __shfl_xor(ssum, off, 64);
    }
    if (t < 16) {
        const float inv = 1.f / (ssum + 1e-16f);
        const int c0 = 8 * q;
        float va[8] = {a0, a1, a2, a3, a4, a5, a6, a7};
        uint32 pk[4];
#pragma unroll
        for (int i = 0; i < 8; i += 2) {
            float v0 = va[i] * inv + b[c0 + i];
            float v1 = va[i + 1] * inv + b[c0 + i + 1];
            v0 = fmaxf((v0 - mu[c0 + i]) * rsqrtf(var[c0 + i] + BN_EPS) * g[c0 + i] + be[c0 + i], 0.f);
            v1 = fmaxf((v1 - mu[c0 + i + 1]) * rsqrtf(var[c0 + i + 1] + BN_EPS) * g[c0 + i + 1] + be[c0 + i + 1], 0.f);
            pk[i >> 1] = (uint32)f2bf(v0) | ((uint32)f2bf(v1) << 16);
        }
        uint4 r = make_uint4(pk[0], pk[1], pk[2], pk[3]);
        *(uint4*)(outb + (size_t)node * 128 + c0) = r;
    }
}

// ====== layer-2 gather: softmax-agg + head-mean + bias + BN -> node_out ======
// 16 lanes per edge (4 streams), 4 channels/lane (uint2).
__global__ __launch_bounds__(256) void gat_gather2(
    const int* __restrict__ base, const int* __restrict__ csr_src, int Etot, int N,
    const ushort16* __restrict__ h2, const float4* __restrict__ att,
    const float2* __restrict__ asc,
    const float* __restrict__ b2, const float* __restrict__ g, const float* __restrict__ be,
    const float* __restrict__ mu, const float* __restrict__ var,
    float* __restrict__ node_out) {
    const int node = __builtin_amdgcn_readfirstlane(blockIdx.x * 4 + (threadIdx.x >> 6));
    if (node >= N) return;
    const int t = threadIdx.x & 63;
    const int sub = t >> 4;    // edge stream
    const int q = t & 15;      // channels 4q..4q+3
    const int hh = q >> 3;     // head
    const int beg = base[node];
    const int end = (node + 1 < N) ? base[node + 1] : Etot;
    const int deg = end - beg;
    const int nk = (deg - sub + 3) >> 2;
    const int nkmax = (deg + 3) >> 2;
    const float4 adn = att[node];
    const float advh = hh ? adn.w : adn.z;

    float a0 = 0.f, a1 = 0.f, a2 = 0.f, a3 = 0.f, ssum = 0.f;
    constexpr int U = 4;
    for (int k = 0; k < nkmax; k += U) {
        int sidx[U];
        float msk[U];
#pragma unroll
        for (int j = 0; j < U; ++j) {
            int kk = k + j;
            bool ok = kk < nk;
            sidx[j] = csr_src[beg + (ok ? 4 * kk + sub : 0)];
            msk[j] = ok ? 1.f : 0.f;
        }
        float2 av[U];
        uint2 hv[U];
#pragma unroll
        for (int j = 0; j < U; ++j) {
            av[j] = asc[sidx[j]];
            hv[j] = *(const uint2*)(h2 + (size_t)sidx[j] * 64 + 4 * q);
        }
#pragma unroll
        for (int j = 0; j < U; ++j) {
            float ev = (hh ? av[j].y : av[j].x) + advh;
            ev = ev > 0.f ? ev : NEG_SLOPE * ev;
            float ex = __expf(ev) * msk[j];
            a0 += ex * bfu_lo(hv[j].x);
            a1 += ex * bfu_hi(hv[j].x);
            a2 += ex * bfu_lo(hv[j].y);
            a3 += ex * bfu_hi(hv[j].y);
            ssum += ex;
        }
    }
#pragma unroll
    for (int off = 16; off <= 32; off <<= 1) {
        a0 += __shfl_xor(a0, off, 64);
        a1 += __shfl_xor(a1, off, 64);
        a2 += __shfl_xor(a2, off, 64);
        a3 += __shfl_xor(a3, off, 64);
        ssum += __shfl_xor(ssum, off, 64);
    }
    const float inv = 1.f / (ssum + 1e-16f);
    float v0 = a0 * inv, v1 = a1 * inv, v2 = a2 * inv, v3 = a3 * inv;
    // head mean: channel 4q+32 lives as v_i of lane (q+8)
    const int src = (t & 15) + 8;
    float p0 = __shfl(v0, src, 64);
    float p1 = __shfl(v1, src, 64);
    float p2 = __shfl(v2, src, 64);
    float p3 = __shfl(v3, src, 64);
    if (t < 8) {
        const int c0 = 4 * t;
        float m0 = 0.5f * (v0 + p0) + b2[c0];
        float m1 = 0.5f * (v1 + p1) + b2[c0 + 1];
        float m2 = 0.5f * (v2 + p2) + b2[c0 + 2];
        float m3 = 0.5f * (v3 + p3) + b2[c0 + 3];
        m0 = (m0 - mu[c0]) * rsqrtf(var[c0] + BN_EPS) * g[c0] + be[c0];
        m1 = (m1 - mu[c0 + 1]) * rsqrtf(var[c0 + 1] + BN_EPS) * g[c0 + 1] + be[c0 + 1];
        m2 = (m2 - mu[c0 + 2]) * rsqrtf(var[c0 + 2] + BN_EPS) * g[c0 + 2] + be[c0 + 2];
        m3 = (m3 - mu[c0 + 3]) * rsqrtf(var[c0 + 3] + BN_EPS) * g[c0 + 3] + be[c0 + 3];
        *(float4*)(node_out + (size_t)node * 32 + c0) = make_float4(m0, m1, m2, m3);
    }
}

// ============ block-per-graph: mean over nodes + log_softmax (32 classes) ============
__global__ __launch_bounds__(256) void pool_logsoftmax(
    const float* __restrict__ node_out, const int* __restrict__ gstart,
    float* __restrict__ out) {
    const int gidx = blockIdx.x;
    const int tid = threadIdx.x;
    const int c = tid & 31, r = tid >> 5;
    const int n0 = gstart[gidx], n1 = gstart[gidx + 1];
    float s = 0.f;
    for (int n = n0 + r; n < n1; n += 8) s += node_out[(size_t)n * 32 + c];
    __shared__ float red[8][32];
    red[r][c] = s;
    __syncthreads();
    if (r == 0) {
        float tot = red[0][c];
#pragma unroll
        for (int k = 1; k < 8; ++k) tot += red[k][c];
        float v = tot / fmaxf((float)(n1 - n0), 1.f);
        float m = v;
#pragma unroll
        for (int off = 16; off >= 1; off >>= 1) m = fmaxf(m, __shfl_xor(m, off, 64));
        float ex = __expf(v - m);
        float ssum = ex;
#pragma unroll
        for (int off = 16; off >= 1; off >>= 1) ssum += __shfl_xor(ssum, off, 64);
        out[gidx * 32 + c] = v - m - logf(ssum);
    }
}

extern "C" void kernel_launch(void* const* d_in, const int* in_sizes, int n_in,
                              void* d_out, int out_size, void* d_ws, size_t ws_size,
                              hipStream_t stream) {
    const float* x   = (const float*)d_in[0];
    const int* ei    = (const int*)d_in[1];
    const int* batch = (const int*)d_in[2];
    const float* W1  = (const float*)d_in[3];
    const float* as1 = (const float*)d_in[4];
    const float* ad1 = (const float*)d_in[5];
    const float* b1  = (const float*)d_in[6];
    const float* g1  = (const float*)d_in[7];
    const float* be1 = (const float*)d_in[8];
    const float* mu1 = (const float*)d_in[9];
    const float* vr1 = (const float*)d_in[10];
    const float* W2  = (const float*)d_in[11];
    const float* as2 = (const float*)d_in[12];
    const float* ad2 = (const float*)d_in[13];
    const float* b2  = (const float*)d_in[14];
    const float* g2  = (const float*)d_in[15];
    const float* be2 = (const float*)d_in[16];
    const float* mu2 = (const float*)d_in[17];
    const float* vr2 = (const float*)d_in[18];
    float* out = (float*)d_out;

    const int N = in_sizes[0] / 128;
    const int E = in_sizes[1] / 2;
    const int Etot = E + N;
    const int G = out_size / 32;
    const int nbuck = (N + (1 << BSHIFT) - 1) >> BSHIFT;
    const int chunk = (Etot + P_PART - 1) / P_PART;
    const int M = nbuck * P_PART;
    const int ntile = (N + 15) / 16;
    const int gemm_grid = (ntile + 3) / 4;

    // ---- workspace layout (units: floats; keep every region 16B-aligned) ----
    float* p = (float*)d_ws;
    size_t o = 0;
    auto al = [&]() { o = (o + 3) & ~(size_t)3; };
    ushort16* h1b   = (ushort16*)(p + o); o += (size_t)N * 64;  al();  // N*128 bf16
    ushort16* agg1b = (ushort16*)(p + o); o += (size_t)N * 64;  al();  // N*128 bf16
    ushort16* h2b   = (ushort16*)(p + o); o += (size_t)N * 32;  al();  // N*64 bf16
    float4* att1 = (float4*)(p + o); o += (size_t)N * 4;  al();
    float4* att2 = (float4*)(p + o); o += (size_t)N * 4;  al();
    float2* asc1 = (float2*)(p + o); o += (size_t)N * 2;  al();
    float2* asc2 = (float2*)(p + o); o += (size_t)N * 2;  al();
    float* nodeo = p + o; o += (size_t)N * 32; al();
    ushort16* wt1 = (ushort16*)(p + o); o += (size_t)144 * 64; al();   // 144x128 bf16
    ushort16* wt2 = (ushort16*)(p + o); o += (size_t)80 * 64;  al();   // 80x128 bf16
    int* csr_src = (int*)(p + o); o += (size_t)Etot; al();
    uint32* ebuf = (uint32*)(p + o); o += (size_t)Etot; al();
    int* base    = (int*)(p + o); o += (size_t)N;    al();
    int* hist    = (int*)(p + o); o += (size_t)M;    al();
    int* rowtot  = (int*)(p + o); o += (size_t)nbuck + 4; al();
    int* bbase   = (int*)(p + o); o += (size_t)nbuck + 4; al();
    int* gstart  = (int*)(p + o); o += (size_t)G + 4; al();
    // (no zero-init needed: every buffer is fully written before it is read)

    // ---- CSR build: histogram -> row scan -> total scan -> rank scatter -> place ----
    hist_part<<<P_PART, 256, 0, stream>>>(ei, E, Etot, nbuck, chunk, hist);
    row_scan<<<nbuck, P_PART, 0, stream>>>(hist, rowtot);
    tot_scan<<<1, 512, 0, stream>>>(rowtot, bbase, nbuck, Etot);
    rank_scatter<<<P_PART, 256, 0, stream>>>(ei, E, Etot, nbuck, chunk, hist, bbase, ebuf);
    bucket_place<<<nbuck, 256, 0, stream>>>(bbase, ebuf, N, base, csr_src);
    // ---- graph bounds + weight pack ----
    graph_bounds<<<(G + 256) / 256, 256, 0, stream>>>(batch, N, G, gstart);
    pack_w<128, 64><<<144, 128, 0, stream>>>(W1, as1, ad1, wt1);
    pack_w<64, 32><<<80, 128, 0, stream>>>(W2, as2, ad2, wt2);

    // ---- layer 1 ----
    gemm_mfma<128, 9, true><<<gemm_grid, 256, 0, stream>>>(x, wt1, h1b, att1, asc1, N);
    gat_gather1<<<(N + 3) / 4, 256, 0, stream>>>(base, csr_src, Etot, N, h1b, att1, asc1,
                                                 b1, g1, be1, mu1, vr1, agg1b);
    // ---- layer 2 ----
    gemm_mfma<64, 5, false><<<gemm_grid, 256, 0, stream>>>(agg1b, wt2, h2b, att2, asc2, N);
    gat_gather2<<<(N + 3) / 4, 256, 0, stream>>>(base, csr_src, Etot, N, h2b, att2, asc2,
                                                 b2, g2, be2, mu2, vr2, nodeo);

    // ---- epilogue ----
    pool_logsoftmax<<<G, 256, 0, stream>>>(nodeo, gstart, out);
}

// Round 11
// 249.950 us; speedup vs baseline: 3.7198x; 1.0312x over previous
//
#include <hip/hip_runtime.h>
#include <hip/hip_bf16.h>

#define NEG_SLOPE 0.2f
#define BN_EPS 1e-5f
#define BSHIFT 7          // 128 nodes per bucket; src packed in low 25 bits (N < 2^25)
#define P_PART 256        // scatter partitions
#define MAXB 512          // max buckets supported (N <= 65536)

typedef unsigned int uint32;
typedef unsigned short ushort16;
typedef __attribute__((ext_vector_type(8))) short bf16x8;
typedef __attribute__((ext_vector_type(4))) float f32x4;

__device__ __forceinline__ ushort16 f2bf(float f) {
    uint32 u = __float_as_uint(f);
    u = (u + 0x7fff + ((u >> 16) & 1)) >> 16;  // round-to-nearest-even
    return (ushort16)u;
}
__device__ __forceinline__ float bfu_lo(uint32 u) { return __uint_as_float(u << 16); }
__device__ __forceinline__ float bfu_hi(uint32 u) { return __uint_as_float(u & 0xffff0000u); }

// ====================== CSR construction (no global atomics) ======================
// Phase 1: per-partition bucket histogram -> hist[b][p] (b-major).
__global__ __launch_bounds__(256) void hist_part(const int* __restrict__ ei, int E, int Etot,
                                                 int nbuck, int chunk, int* __restrict__ hist) {
    const int p = blockIdx.x;
    __shared__ int lh[MAXB];
    for (int i = threadIdx.x; i < nbuck; i += 256) lh[i] = 0;
    __syncthreads();
    const int beg = p * chunk;
    const int end = min(beg + chunk, Etot);
    for (int i = beg + threadIdx.x; i < end; i += 256) {
        int d = (i < E) ? ei[E + i] : i - E;
        atomicAdd(&lh[d >> BSHIFT], 1);
    }
    __syncthreads();
    for (int i = threadIdx.x; i < nbuck; i += 256) hist[(size_t)i * P_PART + p] = lh[i];
}

// Phase 2a: per-bucket exclusive scan over its 256 partition counts (block per bucket).
__global__ __launch_bounds__(P_PART) void row_scan(int* __restrict__ hist,
                                                   int* __restrict__ rowtot) {
    const int b = blockIdx.x;
    __shared__ int s[P_PART];
    const int t = threadIdx.x;
    int v = hist[(size_t)b * P_PART + t];
    s[t] = v;
    __syncthreads();
    for (int off = 1; off < P_PART; off <<= 1) {
        int u = (t >= off) ? s[t - off] : 0;
        __syncthreads();
        s[t] += u;
        __syncthreads();
    }
    hist[(size_t)b * P_PART + t] = s[t] - v;  // exclusive within bucket
    if (t == P_PART - 1) rowtot[b] = s[t];
}

// Phase 2b: exclusive scan of bucket totals (single small block).
__global__ __launch_bounds__(512) void tot_scan(const int* __restrict__ rowtot,
                                                int* __restrict__ bbase, int nbuck, int Etot) {
    __shared__ int s[512];
    const int t = threadIdx.x;
    int v = (t < nbuck) ? rowtot[t] : 0;
    s[t] = v;
    __syncthreads();
    for (int off = 1; off < 512; off <<= 1) {
        int u = (t >= off) ? s[t - off] : 0;
        __syncthreads();
        s[t] += u;
        __syncthreads();
    }
    if (t < nbuck) bbase[t] = s[t] - v;
    if (t == 0) bbase[nbuck] = Etot;
}

// Phase 3: re-read edges; place into ebuf via LDS cursors (disjoint (b,p) ranges).
__global__ __launch_bounds__(256) void rank_scatter(const int* __restrict__ ei, int E, int Etot,
                                                    int nbuck, int chunk,
                                                    const int* __restrict__ hist,
                                                    const int* __restrict__ bbase,
                                                    uint32* __restrict__ ebuf) {
    const int p = blockIdx.x;
    __shared__ int cur[MAXB];
    for (int i = threadIdx.x; i < nbuck; i += 256)
        cur[i] = bbase[i] + hist[(size_t)i * P_PART + p];
    __syncthreads();
    const int beg = p * chunk;
    const int end = min(beg + chunk, Etot);
    for (int i = beg + threadIdx.x; i < end; i += 256) {
        int s_, d_;
        if (i < E) { s_ = ei[i]; d_ = ei[E + i]; }
        else       { s_ = d_ = i - E; }
        int pos = atomicAdd(&cur[d_ >> BSHIFT], 1);
        ebuf[pos] = ((uint32)(d_ & ((1 << BSHIFT) - 1)) << 25) | (uint32)s_;
    }
}

// Phase 4: block per bucket. LDS node-degree histogram + 128-wide scan gives
// base[] directly, then places edges into the bucket's csr window (LDS cursors).
__global__ __launch_bounds__(256) void bucket_place(
    const int* __restrict__ bbase, const uint32* __restrict__ ebuf, int N,
    int* __restrict__ base, int* __restrict__ csr_src) {
    const int bk = blockIdx.x;
    __shared__ int ldeg[1 << BSHIFT];
    __shared__ int sscan[1 << BSHIFT];
    __shared__ int lcur[1 << BSHIFT];
    const int t = threadIdx.x;
    if (t < (1 << BSHIFT)) { ldeg[t] = 0; lcur[t] = 0; }
    __syncthreads();
    const int beg = bbase[bk], end = bbase[bk + 1];
    for (int i = beg + t; i < end; i += 256) atomicAdd(&ldeg[ebuf[i] >> 25], 1);
    __syncthreads();
    if (t < 128) sscan[t] = ldeg[t];
    __syncthreads();
    for (int off = 1; off < 128; off <<= 1) {
        int v = 0;
        if (t < 128 && t >= off) v = sscan[t - off];
        __syncthreads();
        if (t < 128) sscan[t] += v;
        __syncthreads();
    }
    if (t < 128) {
        int node = (bk << BSHIFT) + t;
        if (node < N) base[node] = beg + sscan[t] - ldeg[t];
    }
    __syncthreads();
    for (int i = beg + t; i < end; i += 256) {
        uint32 pk = ebuf[i];
        int dl = (int)(pk >> 25);
        int s_ = (int)(pk & 0x1FFFFFFu);
        int pos = beg + (sscan[dl] - ldeg[dl]) + atomicAdd(&lcur[dl], 1);
        csr_src[pos] = s_;
    }
}

// gstart[g] = first node with batch[node] >= g (batch sorted); gstart[G] = N.
__global__ void graph_bounds(const int* __restrict__ batch, int N, int G,
                             int* __restrict__ gstart) {
    int g = blockIdx.x * blockDim.x + threadIdx.x;
    if (g > G) return;
    if (g == G) { gstart[G] = N; return; }
    int lo = 0, hi = N;
    while (lo < hi) { int mid = (lo + hi) >> 1; if (batch[mid] < g) lo = mid + 1; else hi = mid; }
    gstart[g] = lo;
}

// ================== pack W (+ attention columns) transposed, bf16 ==================
template <int OC, int C>
__global__ void pack_w(const float* __restrict__ W, const float* __restrict__ a_s,
                       const float* __restrict__ a_d, ushort16* __restrict__ wt) {
    const int col = blockIdx.x;
    const int k = threadIdx.x;  // 0..127
    float v = 0.f;
    if (col < OC) {
        v = W[k * OC + col];
    } else if (col < OC + 2) {
        int hh = col - OC;
        float s = 0.f;
        for (int c = 0; c < C; ++c) s += W[k * OC + hh * C + c] * a_s[hh * C + c];
        v = s;
    } else if (col < OC + 4) {
        int hh = col - OC - 2;
        float s = 0.f;
        for (int c = 0; c < C; ++c) s += W[k * OC + hh * C + c] * a_d[hh * C + c];
        v = s;
    }
    wt[(size_t)col * 128 + k] = f2bf(v);
}

// ==================== MFMA GEMM: h = x @ Wext (K=128) ====================
// att = (as_h0, as_h1, ad_h0, ad_h1) fp32; asc = (as_h0, as_h1) duplicate for gathers.
template <int OC, int NT, bool AF32>
__global__ __launch_bounds__(256) void gemm_mfma(
    const void* __restrict__ xin, const ushort16* __restrict__ wt,
    ushort16* __restrict__ h, float4* __restrict__ att, float2* __restrict__ asc, int N) {
    const int wave = threadIdx.x >> 6, lane = threadIdx.x & 63;
    const int tile = blockIdx.x * 4 + wave;
    if (tile * 16 >= N) return;
    const int m = lane & 15, quad = lane >> 4;
    const int node = tile * 16 + m;

    bf16x8 a[4];
    if (AF32) {
        const float* xr = (const float*)xin + (size_t)node * 128 + quad * 8;
#pragma unroll
        for (int c = 0; c < 4; ++c) {
            float4 u = *(const float4*)(xr + c * 32);
            float4 v = *(const float4*)(xr + c * 32 + 4);
            bf16x8 t;
            t[0] = (short)f2bf(u.x); t[1] = (short)f2bf(u.y);
            t[2] = (short)f2bf(u.z); t[3] = (short)f2bf(u.w);
            t[4] = (short)f2bf(v.x); t[5] = (short)f2bf(v.y);
            t[6] = (short)f2bf(v.z); t[7] = (short)f2bf(v.w);
            a[c] = t;
        }
    } else {
        const ushort16* xr = (const ushort16*)xin + (size_t)node * 128 + quad * 8;
#pragma unroll
        for (int c = 0; c < 4; ++c) a[c] = *(const bf16x8*)(xr + c * 32);
    }

    for (int t = 0; t < NT; ++t) {
        const ushort16* wr = wt + ((size_t)(t * 16 + m)) * 128 + quad * 8;
        bf16x8 b[4];
#pragma unroll
        for (int c = 0; c < 4; ++c) b[c] = *(const bf16x8*)(wr + c * 32);
        f32x4 acc = {0.f, 0.f, 0.f, 0.f};
#pragma unroll
        for (int c = 0; c < 4; ++c)
            acc = __builtin_amdgcn_mfma_f32_16x16x32_bf16(a[c], b[c], acc, 0, 0, 0);
        if (t * 16 < OC) {
#pragma unroll
            for (int r = 0; r < 4; ++r) {
                int nrow = tile * 16 + quad * 4 + r;
                h[(size_t)nrow * OC + t * 16 + m] = f2bf(acc[r]);
            }
        } else if (m < 4) {
#pragma unroll
            for (int r = 0; r < 4; ++r) {
                int nrow = tile * 16 + quad * 4 + r;
                ((float*)(att + nrow))[m] = acc[r];
                if (m < 2) ((float*)(asc + nrow))[m] = acc[r];
            }
        }
    }
}

// ================= layer-1 gather (wave-cooperative two-phase) =================
// Phase 1: lane t computes exp for edge t (both heads) once; denominators via butterfly.
// Phase 2: 16 lanes/edge consume h via bpermute'd sidx/ex (ex=0 masks invalid slots).
__global__ __launch_bounds__(256) void gat_gather1(
    const int* __restrict__ base, const int* __restrict__ csr_src, int Etot, int N,
    const ushort16* __restrict__ h, const float4* __restrict__ att,
    const float2* __restrict__ asc,
    const float* __restrict__ b, const float* __restrict__ g, const float* __restrict__ be,
    const float* __restrict__ mu, const float* __restrict__ var,
    ushort16* __restrict__ outb) {
    const int node = __builtin_amdgcn_readfirstlane(blockIdx.x * 4 + (threadIdx.x >> 6));
    if (node >= N) return;
    const int t = threadIdx.x & 63;
    const int sub = t >> 4;    // edge stream 0..3
    const int q = t & 15;      // channels 8q..8q+7
    const int hh = q >> 3;     // head
    const int beg = base[node];
    const int end = (node + 1 < N) ? base[node + 1] : Etot;
    const int deg = end - beg;
    const float4 adn = att[node];

    float a0 = 0.f, a1 = 0.f, a2 = 0.f, a3 = 0.f;
    float a4 = 0.f, a5 = 0.f, a6 = 0.f, a7 = 0.f;
    float ssum0 = 0.f, ssum1 = 0.f;

    for (int c0e = 0; c0e < deg; c0e += 64) {
        // ---- phase 1: one edge per lane ----
        const int rel = c0e + t;
        const bool ok = rel < deg;
        const int sidxme = csr_src[beg + (ok ? rel : 0)];
        const float2 av = asc[sidxme];
        float e0 = av.x + adn.z, e1 = av.y + adn.w;
        e0 = e0 > 0.f ? e0 : NEG_SLOPE * e0;
        e1 = e1 > 0.f ? e1 : NEG_SLOPE * e1;
        const float x0 = ok ? __expf(e0) : 0.f;
        const float x1 = ok ? __expf(e1) : 0.f;
        float r0 = x0, r1 = x1;
#pragma unroll
        for (int off = 1; off < 64; off <<= 1) {
            r0 += __shfl_xor(r0, off, 64);
            r1 += __shfl_xor(r1, off, 64);
        }
        ssum0 += r0;
        ssum1 += r1;
        // ---- phase 2: consume ----
        const int degc = min(deg - c0e, 64);
        const int kkmax = (degc + 3) >> 2;
        for (int kk = 0; kk < kkmax; kk += 4) {
            int sidx[4];
            float exv[4];
            uint4 hv[4];
#pragma unroll
            for (int j = 0; j < 4; ++j) {
                int sl = min(4 * (kk + j) + sub, 63);
                sidx[j] = __shfl(sidxme, sl, 64);
                float f0 = __shfl(x0, sl, 64);
                float f1 = __shfl(x1, sl, 64);
                exv[j] = hh ? f1 : f0;
                hv[j] = *(const uint4*)(h + (size_t)sidx[j] * 128 + 8 * q);
            }
#pragma unroll
            for (int j = 0; j < 4; ++j) {
                const float ex = exv[j];
                a0 += ex * bfu_lo(hv[j].x);
                a1 += ex * bfu_hi(hv[j].x);
                a2 += ex * bfu_lo(hv[j].y);
                a3 += ex * bfu_hi(hv[j].y);
                a4 += ex * bfu_lo(hv[j].z);
                a5 += ex * bfu_hi(hv[j].z);
                a6 += ex * bfu_lo(hv[j].w);
                a7 += ex * bfu_hi(hv[j].w);
            }
        }
    }
    // reduce the 4 edge streams
#pragma unroll
    for (int off = 16; off <= 32; off <<= 1) {
        a0 += __shfl_xor(a0, off, 64);
        a1 += __shfl_xor(a1, off, 64);
        a2 += __shfl_xor(a2, off, 64);
        a3 += __shfl_xor(a3, off, 64);
        a4 += __shfl_xor(a4, off, 64);
        a5 += __shfl_xor(a5, off, 64);
        a6 += __shfl_xor(a6, off, 64);
        a7 += __shfl_xor(a7, off, 64);
    }
    if (t < 16) {
        const float inv = 1.f / ((hh ? ssum1 : ssum0) + 1e-16f);
        const int c0 = 8 * q;
        float va[8] = {a0, a1, a2, a3, a4, a5, a6, a7};
        uint32 pk[4];
#pragma unroll
        for (int i = 0; i < 8; i += 2) {
            float v0 = va[i] * inv + b[c0 + i];
            float v1 = va[i + 1] * inv + b[c0 + i + 1];
            v0 = fmaxf((v0 - mu[c0 + i]) * rsqrtf(var[c0 + i] + BN_EPS) * g[c0 + i] + be[c0 + i], 0.f);
            v1 = fmaxf((v1 - mu[c0 + i + 1]) * rsqrtf(var[c0 + i + 1] + BN_EPS) * g[c0 + i + 1] + be[c0 + i + 1], 0.f);
            pk[i >> 1] = (uint32)f2bf(v0) | ((uint32)f2bf(v1) << 16);
        }
        uint4 r = make_uint4(pk[0], pk[1], pk[2], pk[3]);
        *(uint4*)(outb + (size_t)node * 128 + c0) = r;
    }
}

// ====== layer-2 gather (two-phase): softmax-agg + head-mean + bias + BN -> node_out ======
__global__ __launch_bounds__(256) void gat_gather2(
    const int* __restrict__ base, const int* __restrict__ csr_src, int Etot, int N,
    const ushort16* __restrict__ h2, const float4* __restrict__ att,
    const float2* __restrict__ asc,
    const float* __restrict__ b2, const float* __restrict__ g, const float* __restrict__ be,
    const float* __restrict__ mu, const float* __restrict__ var,
    float* __restrict__ node_out) {
    const int node = __builtin_amdgcn_readfirstlane(blockIdx.x * 4 + (threadIdx.x >> 6));
    if (node >= N) return;
    const int t = threadIdx.x & 63;
    const int sub = t >> 4;    // edge stream
    const int q = t & 15;      // channels 4q..4q+3
    const int hh = q >> 3;     // head
    const int beg = base[node];
    const int end = (node + 1 < N) ? base[node + 1] : Etot;
    const int deg = end - beg;
    const float4 adn = att[node];

    float a0 = 0.f, a1 = 0.f, a2 = 0.f, a3 = 0.f;
    float ssum0 = 0.f, ssum1 = 0.f;

    for (int c0e = 0; c0e < deg; c0e += 64) {
        const int rel = c0e + t;
        const bool ok = rel < deg;
        const int sidxme = csr_src[beg + (ok ? rel : 0)];
        const float2 av = asc[sidxme];
        float e0 = av.x + adn.z, e1 = av.y + adn.w;
        e0 = e0 > 0.f ? e0 : NEG_SLOPE * e0;
        e1 = e1 > 0.f ? e1 : NEG_SLOPE * e1;
        const float x0 = ok ? __expf(e0) : 0.f;
        const float x1 = ok ? __expf(e1) : 0.f;
        float r0 = x0, r1 = x1;
#pragma unroll
        for (int off = 1; off < 64; off <<= 1) {
            r0 += __shfl_xor(r0, off, 64);
            r1 += __shfl_xor(r1, off, 64);
        }
        ssum0 += r0;
        ssum1 += r1;
        const int degc = min(deg - c0e, 64);
        const int kkmax = (degc + 3) >> 2;
        for (int kk = 0; kk < kkmax; kk += 4) {
            int sidx[4];
            float exv[4];
            uint2 hv[4];
#pragma unroll
            for (int j = 0; j < 4; ++j) {
                int sl = min(4 * (kk + j) + sub, 63);
                sidx[j] = __shfl(sidxme, sl, 64);
                float f0 = __shfl(x0, sl, 64);
                float f1 = __shfl(x1, sl, 64);
                exv[j] = hh ? f1 : f0;
                hv[j] = *(const uint2*)(h2 + (size_t)sidx[j] * 64 + 4 * q);
            }
#pragma unroll
            for (int j = 0; j < 4; ++j) {
                const float ex = exv[j];
                a0 += ex * bfu_lo(hv[j].x);
                a1 += ex * bfu_hi(hv[j].x);
                a2 += ex * bfu_lo(hv[j].y);
                a3 += ex * bfu_hi(hv[j].y);
            }
        }
    }
#pragma unroll
    for (int off = 16; off <= 32; off <<= 1) {
        a0 += __shfl_xor(a0, off, 64);
        a1 += __shfl_xor(a1, off, 64);
        a2 += __shfl_xor(a2, off, 64);
        a3 += __shfl_xor(a3, off, 64);
    }
    const float inv = 1.f / ((hh ? ssum1 : ssum0) + 1e-16f);
    float v0 = a0 * inv, v1 = a1 * inv, v2 = a2 * inv, v3 = a3 * inv;
    // head mean: channel 4q+32 lives as v_i of lane (q+8)
    const int src = (t & 15) + 8;
    float p0 = __shfl(v0, src, 64);
    float p1 = __shfl(v1, src, 64);
    float p2 = __shfl(v2, src, 64);
    float p3 = __shfl(v3, src, 64);
    if (t < 8) {
        const int c0 = 4 * t;
        float m0 = 0.5f * (v0 + p0) + b2[c0];
        float m1 = 0.5f * (v1 + p1) + b2[c0 + 1];
        float m2 = 0.5f * (v2 + p2) + b2[c0 + 2];
        float m3 = 0.5f * (v3 + p3) + b2[c0 + 3];
        m0 = (m0 - mu[c0]) * rsqrtf(var[c0] + BN_EPS) * g[c0] + be[c0];
        m1 = (m1 - mu[c0 + 1]) * rsqrtf(var[c0 + 1] + BN_EPS) * g[c0 + 1] + be[c0 + 1];
        m2 = (m2 - mu[c0 + 2]) * rsqrtf(var[c0 + 2] + BN_EPS) * g[c0 + 2] + be[c0 + 2];
        m3 = (m3 - mu[c0 + 3]) * rsqrtf(var[c0 + 3] + BN_EPS) * g[c0 + 3] + be[c0 + 3];
        *(float4*)(node_out + (size_t)node * 32 + c0) = make_float4(m0, m1, m2, m3);
    }
}

// ============ block-per-graph: mean over nodes + log_softmax (32 classes) ============
__global__ __launch_bounds__(256) void pool_logsoftmax(
    const float* __restrict__ node_out, const int* __restrict__ gstart,
    float* __restrict__ out) {
    const int gidx = blockIdx.x;
    const int tid = threadIdx.x;
    const int c = tid & 31, r = tid >> 5;
    const int n0 = gstart[gidx], n1 = gstart[gidx + 1];
    float s = 0.f;
    for (int n = n0 + r; n < n1; n += 8) s += node_out[(size_t)n * 32 + c];
    __shared__ float red[8][32];
    red[r][c] = s;
    __syncthreads();
    if (r == 0) {
        float tot = red[0][c];
#pragma unroll
        for (int k = 1; k < 8; ++k) tot += red[k][c];
        float v = tot / fmaxf((float)(n1 - n0), 1.f);
        float m = v;
#pragma unroll
        for (int off = 16; off >= 1; off >>= 1) m = fmaxf(m, __shfl_xor(m, off, 64));
        float ex = __expf(v - m);
        float ssum = ex;
#pragma unroll
        for (int off = 16; off >= 1; off >>= 1) ssum += __shfl_xor(ssum, off, 64);
        out[gidx * 32 + c] = v - m - logf(ssum);
    }
}

extern "C" void kernel_launch(void* const* d_in, const int* in_sizes, int n_in,
                              void* d_out, int out_size, void* d_ws, size_t ws_size,
                              hipStream_t stream) {
    const float* x   = (const float*)d_in[0];
    const int* ei    = (const int*)d_in[1];
    const int* batch = (const int*)d_in[2];
    const float* W1  = (const float*)d_in[3];
    const float* as1 = (const float*)d_in[4];
    const float* ad1 = (const float*)d_in[5];
    const float* b1  = (const float*)d_in[6];
    const float* g1  = (const float*)d_in[7];
    const float* be1 = (const float*)d_in[8];
    const float* mu1 = (const float*)d_in[9];
    const float* vr1 = (const float*)d_in[10];
    const float* W2  = (const float*)d_in[11];
    const float* as2 = (const float*)d_in[12];
    const float* ad2 = (const float*)d_in[13];
    const float* b2  = (const float*)d_in[14];
    const float* g2  = (const float*)d_in[15];
    const float* be2 = (const float*)d_in[16];
    const float* mu2 = (const float*)d_in[17];
    const float* vr2 = (const float*)d_in[18];
    float* out = (float*)d_out;

    const int N = in_sizes[0] / 128;
    const int E = in_sizes[1] / 2;
    const int Etot = E + N;
    const int G = out_size / 32;
    const int nbuck = (N + (1 << BSHIFT) - 1) >> BSHIFT;
    const int chunk = (Etot + P_PART - 1) / P_PART;
    const int M = nbuck * P_PART;
    const int ntile = (N + 15) / 16;
    const int gemm_grid = (ntile + 3) / 4;

    // ---- workspace layout (units: floats; keep every region 16B-aligned) ----
    float* p = (float*)d_ws;
    size_t o = 0;
    auto al = [&]() { o = (o + 3) & ~(size_t)3; };
    ushort16* h1b   = (ushort16*)(p + o); o += (size_t)N * 64;  al();  // N*128 bf16
    ushort16* agg1b = (ushort16*)(p + o); o += (size_t)N * 64;  al();  // N*128 bf16
    ushort16* h2b   = (ushort16*)(p + o); o += (size_t)N * 32;  al();  // N*64 bf16
    float4* att1 = (float4*)(p + o); o += (size_t)N * 4;  al();
    float4* att2 = (float4*)(p + o); o += (size_t)N * 4;  al();
    float2* asc1 = (float2*)(p + o); o += (size_t)N * 2;  al();
    float2* asc2 = (float2*)(p + o); o += (size_t)N * 2;  al();
    float* nodeo = p + o; o += (size_t)N * 32; al();
    ushort16* wt1 = (ushort16*)(p + o); o += (size_t)144 * 64; al();   // 144x128 bf16
    ushort16* wt2 = (ushort16*)(p + o); o += (size_t)80 * 64;  al();   // 80x128 bf16
    int* csr_src = (int*)(p + o); o += (size_t)Etot; al();
    uint32* ebuf = (uint32*)(p + o); o += (size_t)Etot; al();
    int* base    = (int*)(p + o); o += (size_t)N;    al();
    int* hist    = (int*)(p + o); o += (size_t)M;    al();
    int* rowtot  = (int*)(p + o); o += (size_t)nbuck + 4; al();
    int* bbase   = (int*)(p + o); o += (size_t)nbuck + 4; al();
    int* gstart  = (int*)(p + o); o += (size_t)G + 4; al();
    // (no zero-init needed: every buffer is fully written before it is read)

    // ---- CSR build: histogram -> row scan -> total scan -> rank scatter -> place ----
    hist_part<<<P_PART, 256, 0, stream>>>(ei, E, Etot, nbuck, chunk, hist);
    row_scan<<<nbuck, P_PART, 0, stream>>>(hist, rowtot);
    tot_scan<<<1, 512, 0, stream>>>(rowtot, bbase, nbuck, Etot);
    rank_scatter<<<P_PART, 256, 0, stream>>>(ei, E, Etot, nbuck, chunk, hist, bbase, ebuf);
    bucket_place<<<nbuck, 256, 0, stream>>>(bbase, ebuf, N, base, csr_src);
    // ---- graph bounds + weight pack ----
    graph_bounds<<<(G + 256) / 256, 256, 0, stream>>>(batch, N, G, gstart);
    pack_w<128, 64><<<144, 128, 0, stream>>>(W1, as1, ad1, wt1);
    pack_w<64, 32><<<80, 128, 0, stream>>>(W2, as2, ad2, wt2);

    // ---- layer 1 ----
    gemm_mfma<128, 9, true><<<gemm_grid, 256, 0, stream>>>(x, wt1, h1b, att1, asc1, N);
    gat_gather1<<<(N + 3) / 4, 256, 0, stream>>>(base, csr_src, Etot, N, h1b, att1, asc1,
                                                 b1, g1, be1, mu1, vr1, agg1b);
    // ---- layer 2 ----
    gemm_mfma<64, 5, false><<<gemm_grid, 256, 0, stream>>>(agg1b, wt2, h2b, att2, asc2, N);
    gat_gather2<<<(N + 3) / 4, 256, 0, stream>>>(base, csr_src, Etot, N, h2b, att2, asc2,
                                                 b2, g2, be2, mu2, vr2, nodeo);

    // ---- epilogue ----
    pool_logsoftmax<<<G, 256, 0, stream>>>(nodeo, gstart, out);
}